// Round 7
// baseline (279.877 us; speedup 1.0000x reference)
//
#include <hip/hip_runtime.h>

// HeavilyCompressedAttention on MI355X (gfx950). R7:
//  - k_gemm256 / k_gemm_out256: 256x256 tile, BK=32, 3 LDS buffers (96KB),
//    2-tile-ahead prefetch with COUNTED vmcnt(8/4/0), 2 barriers per tile,
//    2 compute phases, setprio around MFMA, 4-slot swizzle slot^((r^(r>>2))&3).
//  - epilogues / other kernels unchanged from R6 (verified).

typedef unsigned short u16;
typedef __attribute__((ext_vector_type(8))) short short8;
typedef __attribute__((ext_vector_type(4))) float f32x4;

#define S_LEN 2048
#define HIDN  2048
#define NHEAD 16
#define HDIM  128
#define NCHNK 128
#define NKT   64                      // K tiles of 32
#define SCALE 0.08838834764831845f   // 1/sqrt(128)

__device__ __forceinline__ float bf2f(u16 h) {
  return __uint_as_float(((unsigned)h) << 16);
}
__device__ __forceinline__ u16 f2bf(float f) {
  unsigned u = __float_as_uint(f);
  unsigned r = (u + 0x7fffu + ((u >> 16) & 1u)) >> 16;
  return (u16)r;
}

typedef __attribute__((address_space(3))) unsigned int lds_uint;
typedef __attribute__((address_space(1))) unsigned int glb_uint;
__device__ __forceinline__ void gl_lds16(const void* g, void* l) {
  __builtin_amdgcn_global_load_lds((glb_uint*)(unsigned long long)g,
                                   (lds_uint*)(unsigned)(unsigned long long)l,
                                   16, 0, 0);
}

// ---------------- rope table
__global__ __launch_bounds__(256) void k_rope_table(float* __restrict__ rc, float* __restrict__ rs) {
  int i = blockIdx.x * 256 + threadIdx.x;
  int pos = i >> 5, f = i & 31;
  float inv = __expf(-(float)f * (9.210340371976184f / 32.0f));
  float ang = (float)pos * inv;
  rc[i] = cosf(ang);
  rs[i] = sinf(ang);
}

// ---------------- cast hs f32 -> bf16
__global__ __launch_bounds__(256) void k_cast_hs(const float* __restrict__ src, u16* __restrict__ dst) {
  size_t i4 = ((size_t)blockIdx.x * 256 + threadIdx.x) * 4;
  float4 v = *(const float4*)&src[i4];
  ushort4 o;
  o.x = f2bf(v.x); o.y = f2bf(v.y); o.z = f2bf(v.z); o.w = f2bf(v.w);
  *(ushort4*)&dst[i4] = o;
}

// ---------------- 4 big weight transposes
__global__ __launch_bounds__(256) void k_transpose4(const float* __restrict__ s0, const float* __restrict__ s1,
                                                    const float* __restrict__ s2, const float* __restrict__ s3,
                                                    u16* __restrict__ dqkv, u16* __restrict__ dout) {
  __shared__ float tile[32][33];
  int z = blockIdx.z;
  const float* src = (z == 0) ? s0 : (z == 1) ? s1 : (z == 2) ? s2 : s3;
  u16* dst = (z < 3) ? (dqkv + (size_t)z * HIDN * HIDN) : dout;
  int k0 = blockIdx.x * 32, n0 = blockIdx.y * 32;
  int tx = threadIdx.x, ty = threadIdx.y;
  #pragma unroll
  for (int i = 0; i < 32; i += 8)
    tile[ty + i][tx] = src[(size_t)(k0 + ty + i) * HIDN + (n0 + tx)];
  __syncthreads();
  #pragma unroll
  for (int i = 0; i < 32; i += 8)
    dst[(size_t)(n0 + ty + i) * HIDN + (k0 + tx)] = f2bf(tile[tx][ty + i]);
}

// ---------------- Wk/Wv -> Wkv_t (256 x 2048 bf16)
__global__ __launch_bounds__(256) void k_transpose_w(const float* __restrict__ Wk, const float* __restrict__ Wv,
                                                     u16* __restrict__ Wkv_t) {
  __shared__ float tile[32][33];
  int z = blockIdx.z;
  const float* src = z ? Wv : Wk;
  u16* dst = Wkv_t + (size_t)z * HDIM * 2048;
  int k0 = blockIdx.x * 32, n0 = blockIdx.y * 32;
  int tx = threadIdx.x, ty = threadIdx.y;
  #pragma unroll
  for (int i = 0; i < 32; i += 8)
    tile[ty + i][tx] = src[(size_t)(k0 + ty + i) * HDIM + (n0 + tx)];
  __syncthreads();
  #pragma unroll
  for (int i = 0; i < 32; i += 8)
    dst[(size_t)(n0 + ty + i) * 2048 + (k0 + tx)] = f2bf(tile[tx][ty + i]);
}

// ---------------- chunk logits + softmax + entries (bf16)
__global__ __launch_bounds__(256) void k_chunk_we(const float* __restrict__ hs, const float* __restrict__ Wc,
                                                  const float* __restrict__ bc, u16* __restrict__ entries_bf) {
  __shared__ float red[16][17];
  __shared__ float wgt[16];
  int c = blockIdx.x, tid = threadIdx.x;
  int row = tid >> 4, seg = tid & 15;
  const float* hrow = hs + ((size_t)c * 16 + row) * HIDN;
  float p = 0.f;
  #pragma unroll 8
  for (int k = seg * 128; k < seg * 128 + 128; k += 4) {
    float4 hv = *(const float4*)&hrow[k];
    float4 wv = *(const float4*)&Wc[k];
    p += hv.x * wv.x + hv.y * wv.y + hv.z * wv.z + hv.w * wv.w;
  }
  red[row][seg] = p;
  __syncthreads();
  if (tid < 16) {
    float lg = 0.f;
    #pragma unroll
    for (int j = 0; j < 16; ++j) lg += red[tid][j];
    lg += bc[0];
    float m = lg;
    #pragma unroll
    for (int msk = 1; msk <= 8; msk <<= 1) m = fmaxf(m, __shfl_xor(m, msk));
    float ev = __expf(lg - m);
    float sum = ev;
    #pragma unroll
    for (int msk = 1; msk <= 8; msk <<= 1) sum += __shfl_xor(sum, msk);
    wgt[tid] = ev / sum;
  }
  __syncthreads();
  #pragma unroll
  for (int j = 0; j < 8; ++j) {
    int hb = tid + j * 256;
    float acc = 0.f;
    #pragma unroll
    for (int r = 0; r < 16; ++r)
      acc += wgt[r] * hs[((size_t)c * 16 + r) * HIDN + hb];
    entries_bf[(size_t)c * HIDN + hb] = f2bf(acc);
  }
}

// ============ shared 256x256 BK=32 3-buffer pipelined K-loop (macro-ish via lambdas)
// LDS buffer: A 256x32 u16 at [0,8192), B 256x32 at [8192,16384). 3 buffers.
// swizzle: slot' = slot ^ ((r ^ (r>>2)) & 3)   (2-way max -> free)

// ---------------- 256x256 GEMM for q/lk/lv (+ck/cv block 192)
__global__ __launch_bounds__(512, 2) void k_gemm256(
    const u16* __restrict__ A, const u16* __restrict__ Wt3,
    const u16* __restrict__ entries_bf, const u16* __restrict__ Wkv_t,
    const float* __restrict__ bq, const float* __restrict__ blk, const float* __restrict__ blv,
    const float* __restrict__ bk, const float* __restrict__ bv,
    const float* __restrict__ qn_w, const float* __restrict__ kn_w,
    const float* __restrict__ rc, const float* __restrict__ rs,
    u16* __restrict__ q_out, u16* __restrict__ lk_out, u16* __restrict__ lv_t,
    u16* __restrict__ ck_bf, u16* __restrict__ cv_t) {
  __shared__ __align__(16) u16 lds[49152];     // 96 KB: 3 x 32 KB
  __shared__ float psq[2][4][128];             // 4 KB
  int tid = threadIdx.x, lane = tid & 63;
  int wid = tid >> 6;
  int wr = wid >> 2, wc = wid & 3;             // 2 x 4 waves
  int lin = blockIdx.x;
  int row0, col0, mode;
  const u16 *Ag, *Bg;
  if (lin < 192) {
    int swz = (lin & 7) * 24 + (lin >> 3);     // XCD-bijective 192 = 8*24
    mode = swz >> 6;
    int tile = swz & 63;
    row0 = (tile & 7) * 256;
    col0 = (tile >> 3) * 256;
    Ag = A; Bg = Wt3 + (size_t)mode * HIDN * HIDN;
  } else {
    mode = 3; row0 = 0; col0 = 0;
    Ag = entries_bf; Bg = Wkv_t;
  }
  int rA = lane & 15, kg = lane >> 4;          // kg in [0,4)
  int srow = tid >> 2, sslot = tid & 3;
  int ssl = sslot ^ ((srow ^ (srow >> 2)) & 3);   // inverse swizzle on SOURCE

  f32x4 acc[8][4];
  #pragma unroll
  for (int m = 0; m < 8; ++m)
    #pragma unroll
    for (int n = 0; n < 4; ++n) acc[m][n] = (f32x4){0.f, 0.f, 0.f, 0.f};

  // stage half i (0,1 = A rows i*128..; 2,3 = B rows (i-2)*128..) of K-tile kt -> buffer b
  auto stage = [&](int b, int i, int kt) {
    const u16* src = (i < 2) ? Ag : Bg;
    int rg = ((i < 2) ? row0 : col0) + ((i & 1) * 128) + srow;
    gl_lds16(&src[(size_t)rg * HIDN + kt * 32 + ssl * 8],
             &lds[b * 16384 + i * 4096 + tid * 8]);
  };
  auto rdA = [&](int b, int m) -> short8 {
    int r = wr * 128 + m * 16 + rA;
    int slot = kg ^ ((r ^ (r >> 2)) & 3);
    return *(const short8*)&lds[b * 16384 + r * 32 + slot * 8];
  };
  auto rdB = [&](int b, int n) -> short8 {
    int r = wc * 64 + n * 16 + rA;
    int slot = kg ^ ((r ^ (r >> 2)) & 3);
    return *(const short8*)&lds[b * 16384 + 8192 + r * 32 + slot * 8];
  };

  // prologue: tiles 0,1 -> buffers 0,1
  #pragma unroll
  for (int i = 0; i < 4; ++i) stage(0, i, 0);
  #pragma unroll
  for (int i = 0; i < 4; ++i) stage(1, i, 1);

  for (int u = 0; u < NKT; ++u) {
    int cb = u % 3;
    if (u + 2 < NKT) {
      int b2 = (u + 2) % 3;
      stage(b2, 0, u + 2); stage(b2, 1, u + 2);
      stage(b2, 2, u + 2); stage(b2, 3, u + 2);
    }
    if (u < NKT - 2)       asm volatile("s_waitcnt vmcnt(8)" ::: "memory");
    else if (u == NKT - 2) asm volatile("s_waitcnt vmcnt(4)" ::: "memory");
    else                   asm volatile("s_waitcnt vmcnt(0)" ::: "memory");
    __builtin_amdgcn_sched_barrier(0);
    __builtin_amdgcn_s_barrier();
    // phase 1: m0-3 x n0-3
    short8 Af[4], Bf[4];
    #pragma unroll
    for (int m = 0; m < 4; ++m) Af[m] = rdA(cb, m);
    #pragma unroll
    for (int n = 0; n < 4; ++n) Bf[n] = rdB(cb, n);
    asm volatile("s_waitcnt lgkmcnt(0)" ::: "memory");
    __builtin_amdgcn_sched_barrier(0);
    __builtin_amdgcn_s_setprio(1);
    #pragma unroll
    for (int m = 0; m < 4; ++m)
      #pragma unroll
      for (int n = 0; n < 4; ++n)
        acc[m][n] = __builtin_amdgcn_mfma_f32_16x16x32_bf16(Af[m], Bf[n], acc[m][n], 0, 0, 0);
    __builtin_amdgcn_s_setprio(0);
    // phase 2: m4-7 x n0-3
    #pragma unroll
    for (int m = 0; m < 4; ++m) Af[m] = rdA(cb, m + 4);
    asm volatile("s_waitcnt lgkmcnt(0)" ::: "memory");
    __builtin_amdgcn_sched_barrier(0);
    __builtin_amdgcn_s_setprio(1);
    #pragma unroll
    for (int m = 0; m < 4; ++m)
      #pragma unroll
      for (int n = 0; n < 4; ++n)
        acc[m + 4][n] = __builtin_amdgcn_mfma_f32_16x16x32_bf16(Af[m], Bf[n], acc[m + 4][n], 0, 0, 0);
    __builtin_amdgcn_s_setprio(0);
    __builtin_amdgcn_s_barrier();   // end-of-tile: safe to overwrite cb next iter
  }

  // ---------------- epilogue (unchanged from R6)
  int cl = rA, rbase = kg * 4;
  #pragma unroll
  for (int n = 0; n < 4; ++n) {
    int dl = wc * 64 + n * 16 + cl;
    float bb;
    if (mode == 3)      bb = (dl < 128) ? bk[dl] : bv[dl - 128];
    else if (mode == 0) bb = bq[col0 + dl];
    else if (mode == 1) bb = blk[col0 + dl];
    else                bb = blv[col0 + dl];
    #pragma unroll
    for (int m = 0; m < 8; ++m)
      #pragma unroll
      for (int j = 0; j < 4; ++j) acc[m][n][j] += bb;
  }

  if (mode == 2) {   // lv: transposed (h, d, s) bf16 store
    int hh = (col0 >> 7) + (wc >> 1);
    #pragma unroll
    for (int m = 0; m < 8; ++m) {
      int sb = row0 + wr * 128 + m * 16 + rbase;
      #pragma unroll
      for (int n = 0; n < 4; ++n) {
        int dl = (wc & 1) * 64 + n * 16 + cl;
        ushort4 o;
        o.x = f2bf(acc[m][n][0]);
        o.y = f2bf(acc[m][n][1]);
        o.z = f2bf(acc[m][n][2]);
        o.w = f2bf(acc[m][n][3]);
        *(ushort4*)&lv_t[((size_t)hh * HDIM + dl) * S_LEN + sb] = o;
      }
    }
    return;
  }

  bool is_cv = (mode == 3) && (wc >= 2);
  if (!is_cv) {
    #pragma unroll
    for (int m = 0; m < 8; ++m)
      #pragma unroll
      for (int j = 0; j < 4; ++j) {
        float s2 = acc[m][0][j] * acc[m][0][j] + acc[m][1][j] * acc[m][1][j]
                 + acc[m][2][j] * acc[m][2][j] + acc[m][3][j] * acc[m][3][j];
        s2 += __shfl_xor(s2, 1); s2 += __shfl_xor(s2, 2);
        s2 += __shfl_xor(s2, 4); s2 += __shfl_xor(s2, 8);
        if (cl == 0) psq[wr][wc][m * 16 + rbase + j] = s2;
      }
  }
  __syncthreads();
  if (is_cv) {       // cv: transposed [d][c] store, valid rows 0-127 (wr==0)
    if (wr == 0) {
      #pragma unroll
      for (int m = 0; m < 8; ++m) {
        int cchunk = m * 16 + rbase;
        #pragma unroll
        for (int n = 0; n < 4; ++n) {
          int d = (wc - 2) * 64 + n * 16 + cl;
          #pragma unroll
          for (int j = 0; j < 4; ++j)
            cv_t[(size_t)d * NCHNK + cchunk + j] = f2bf(acc[m][n][j]);
        }
      }
    }
    return;
  }
  // rmsnorm + rope: modes 0 (q), 1 (lk), 3-ck (wc<2)
  {
    const float* nw = (mode == 0) ? qn_w : kn_w;
    int hgrp = wc >> 1;
    float nwv[4];
    #pragma unroll
    for (int n = 0; n < 4; ++n) nwv[n] = nw[(wc & 1) * 64 + n * 16 + cl];
    #pragma unroll
    for (int m = 0; m < 8; ++m)
      #pragma unroll
      for (int j = 0; j < 4; ++j) {
        int r16 = m * 16 + rbase + j;
        int s = row0 + wr * 128 + r16;
        bool valid = (mode != 3) || (s < NCHNK);
        int sc = valid ? s : 0;
        int pos = (mode == 3) ? (sc * 16 + 15) : sc;
        float rr2 = rsqrtf((psq[wr][hgrp * 2][r16] + psq[wr][hgrp * 2 + 1][r16]) * (1.f / 128.f) + 1e-6f);
        float o[4];
        if ((wc & 1) == 0) {
          #pragma unroll
          for (int n = 0; n < 2; ++n) {
            int i = n * 16 + cl;
            float ca = rc[pos * 32 + i], sa = rs[pos * 32 + i];
            float y1 = acc[m][n][j] * rr2 * nwv[n];
            float y2 = acc[m][n + 2][j] * rr2 * nwv[n + 2];
            o[n] = y1 * ca - y2 * sa;
            o[n + 2] = y1 * sa + y2 * ca;
          }
        } else {
          #pragma unroll
          for (int n = 0; n < 4; ++n) o[n] = acc[m][n][j] * rr2 * nwv[n];
        }
        if (valid) {
          u16* dst;
          if (mode == 3) dst = ck_bf + (size_t)s * HDIM + (wc & 1) * 64;
          else {
            u16* dstb = (mode == 0) ? q_out : lk_out;
            dst = dstb + ((size_t)((col0 >> 7) + hgrp) * S_LEN + s) * HDIM + (wc & 1) * 64;
          }
          #pragma unroll
          for (int n = 0; n < 4; ++n) dst[n * 16 + cl] = f2bf(o[n]);
        }
      }
  }
}

// ---------------- out GEMM: same pipelined core, f32 + bias epilogue. grid 64 (8x8)
__global__ __launch_bounds__(512, 2) void k_gemm_out256(const u16* __restrict__ A, const u16* __restrict__ Bt,
                                                        const float* __restrict__ bias, float* __restrict__ C) {
  __shared__ __align__(16) u16 lds[49152];
  int tid = threadIdx.x, lane = tid & 63;
  int wid = tid >> 6;
  int wr = wid >> 2, wc = wid & 3;
  int lin = blockIdx.x;
  int swz = (lin & 7) * 8 + (lin >> 3);        // bijective: 64 = 8*8
  int row0 = (swz & 7) * 256, col0 = (swz >> 3) * 256;
  int rA = lane & 15, kg = lane >> 4;
  int srow = tid >> 2, sslot = tid & 3;
  int ssl = sslot ^ ((srow ^ (srow >> 2)) & 3);

  f32x4 acc[8][4];
  #pragma unroll
  for (int m = 0; m < 8; ++m)
    #pragma unroll
    for (int n = 0; n < 4; ++n) acc[m][n] = (f32x4){0.f, 0.f, 0.f, 0.f};

  auto stage = [&](int b, int i, int kt) {
    const u16* src = (i < 2) ? A : Bt;
    int rg = ((i < 2) ? row0 : col0) + ((i & 1) * 128) + srow;
    gl_lds16(&src[(size_t)rg * HIDN + kt * 32 + ssl * 8],
             &lds[b * 16384 + i * 4096 + tid * 8]);
  };
  auto rdA = [&](int b, int m) -> short8 {
    int r = wr * 128 + m * 16 + rA;
    int slot = kg ^ ((r ^ (r >> 2)) & 3);
    return *(const short8*)&lds[b * 16384 + r * 32 + slot * 8];
  };
  auto rdB = [&](int b, int n) -> short8 {
    int r = wc * 64 + n * 16 + rA;
    int slot = kg ^ ((r ^ (r >> 2)) & 3);
    return *(const short8*)&lds[b * 16384 + 8192 + r * 32 + slot * 8];
  };

  #pragma unroll
  for (int i = 0; i < 4; ++i) stage(0, i, 0);
  #pragma unroll
  for (int i = 0; i < 4; ++i) stage(1, i, 1);

  for (int u = 0; u < NKT; ++u) {
    int cb = u % 3;
    if (u + 2 < NKT) {
      int b2 = (u + 2) % 3;
      stage(b2, 0, u + 2); stage(b2, 1, u + 2);
      stage(b2, 2, u + 2); stage(b2, 3, u + 2);
    }
    if (u < NKT - 2)       asm volatile("s_waitcnt vmcnt(8)" ::: "memory");
    else if (u == NKT - 2) asm volatile("s_waitcnt vmcnt(4)" ::: "memory");
    else                   asm volatile("s_waitcnt vmcnt(0)" ::: "memory");
    __builtin_amdgcn_sched_barrier(0);
    __builtin_amdgcn_s_barrier();
    short8 Af[4], Bf[4];
    #pragma unroll
    for (int m = 0; m < 4; ++m) Af[m] = rdA(cb, m);
    #pragma unroll
    for (int n = 0; n < 4; ++n) Bf[n] = rdB(cb, n);
    asm volatile("s_waitcnt lgkmcnt(0)" ::: "memory");
    __builtin_amdgcn_sched_barrier(0);
    __builtin_amdgcn_s_setprio(1);
    #pragma unroll
    for (int m = 0; m < 4; ++m)
      #pragma unroll
      for (int n = 0; n < 4; ++n)
        acc[m][n] = __builtin_amdgcn_mfma_f32_16x16x32_bf16(Af[m], Bf[n], acc[m][n], 0, 0, 0);
    __builtin_amdgcn_s_setprio(0);
    #pragma unroll
    for (int m = 0; m < 4; ++m) Af[m] = rdA(cb, m + 4);
    asm volatile("s_waitcnt lgkmcnt(0)" ::: "memory");
    __builtin_amdgcn_sched_barrier(0);
    __builtin_amdgcn_s_setprio(1);
    #pragma unroll
    for (int m = 0; m < 4; ++m)
      #pragma unroll
      for (int n = 0; n < 4; ++n)
        acc[m + 4][n] = __builtin_amdgcn_mfma_f32_16x16x32_bf16(Af[m], Bf[n], acc[m + 4][n], 0, 0, 0);
    __builtin_amdgcn_s_setprio(0);
    __builtin_amdgcn_s_barrier();
  }

  int cl = rA, rbase = kg * 4;
  #pragma unroll
  for (int m = 0; m < 8; ++m) {
    int rowb = row0 + wr * 128 + m * 16 + rbase;
    #pragma unroll
    for (int n = 0; n < 4; ++n) {
      int col = col0 + wc * 64 + n * 16 + cl;
      float bb = bias[col];
      #pragma unroll
      for (int j = 0; j < 4; ++j)
        C[(size_t)(rowb + j) * HIDN + col] = acc[m][n][j] + bb;
    }
  }
}

// ---------------- compressed attention (MFMA) -> ctx_c f32 (h,s,d). sink folded in.
__global__ __launch_bounds__(256) void k_cattn(const u16* __restrict__ q_bf, const u16* __restrict__ ck_bf,
                                               const u16* __restrict__ cv_t, const float* __restrict__ sink_k,
                                               const float* __restrict__ sink_v, float* __restrict__ ctx_c) {
  __shared__ __align__(16) u16 kv[21760];
  __shared__ __align__(16) float sc[32][164];
  __shared__ __align__(16) u16 pb[32][168];
  int tid = threadIdx.x, lane = tid & 63, wave = tid >> 6;
  int h = blockIdx.y, s0 = blockIdx.x * 32;
  int cmax = s0 / 16 + 2; if (cmax > 128) cmax = 128;
  int nkeys = cmax + 1;
  int nkt = (nkeys + 15) >> 4, nkc = (nkeys + 31) >> 5;
  const size_t hb = (size_t)h * S_LEN * HDIM;
  int rA = lane & 15, kg8 = (lane >> 4) * 8;
  int qt = wave & 1, wg = wave >> 1;

  short8 aq[4];
  #pragma unroll
  for (int c = 0; c < 4; ++c)
    aq[c] = *(const short8*)&q_bf[hb + (size_t)(s0 + qt * 16 + rA) * HDIM + c * 32 + kg8];

  for (int i = tid; i < cmax * 16; i += 256) {
    int r = i >> 4, cz = (i & 15) * 8;
    *(uint4*)&kv[r * 136 + cz] = *(const uint4*)&ck_bf[r * HDIM + cz];
  }
  if (tid < 128) kv[cmax * 136 + tid] = f2bf(sink_k[h * HDIM + tid]);
  __syncthreads();

  for (int kt = wg; kt < nkt; kt += 2) {
    f32x4 a = (f32x4){0.f, 0.f, 0.f, 0.f};
    #pragma unroll
    for (int c = 0; c < 4; ++c) {
      short8 bk2 = *(const short8*)&kv[(kt * 16 + rA) * 136 + c * 32 + kg8];
      a = __builtin_amdgcn_mfma_f32_16x16x32_bf16(aq[c], bk2, a, 0, 0, 0);
    }
    int rq = qt * 16 + (lane >> 4) * 4;
    #pragma unroll
    for (int j = 0; j < 4; ++j) sc[rq + j][kt * 16 + rA] = a[j];
  }
  __syncthreads();

  {
    int ql = tid >> 3, e = tid & 7, s = s0 + ql;
    int NK = nkc * 32;
    float m = -1e30f;
    for (int i = e; i < NK; i += 8) {
      if (i < nkeys) {
        float raw = sc[ql][i];
        bool valid = (i < cmax) ? (i * 16 + 15 <= s) : true;
        float v = valid ? raw * SCALE : -1e9f;
        sc[ql][i] = v;
        m = fmaxf(m, v);
      }
    }
    m = fmaxf(m, __shfl_xor(m, 1));
    m = fmaxf(m, __shfl_xor(m, 2));
    m = fmaxf(m, __shfl_xor(m, 4));
    float sum = 0.f;
    for (int i = e; i < NK; i += 8) {
      if (i < nkeys) {
        float pv = __expf(sc[ql][i] - m);
        sc[ql][i] = pv;
        sum += pv;
      }
    }
    sum += __shfl_xor(sum, 1);
    sum += __shfl_xor(sum, 2);
    sum += __shfl_xor(sum, 4);
    float inv = 1.f / sum;
    for (int i = e; i < NK; i += 8)
      pb[ql][i] = (i < nkeys) ? f2bf(sc[ql][i] * inv) : (u16)0;
  }
  __syncthreads();

  {
    int d = tid & 127, cstart = tid >> 7;
    u16 sv = f2bf(sink_v[h * HDIM + d]);
    int NC = nkc * 32;
    for (int c = cstart; c < NC; c += 2) {
      u16 v = (c < cmax) ? cv_t[(size_t)d * NCHNK + c] : ((c == cmax) ? sv : (u16)0);
      kv[d * 168 + c] = v;
    }
  }
  __syncthreads();

  {
    f32x4 po[4];
    #pragma unroll
    for (int n = 0; n < 4; ++n) po[n] = (f32x4){0.f, 0.f, 0.f, 0.f};
    for (int kc = 0; kc < nkc; ++kc) {
      short8 pfrag = *(const short8*)&pb[qt * 16 + rA][kc * 32 + kg8];
      #pragma unroll
      for (int n = 0; n < 4; ++n) {
        short8 av = *(const short8*)&kv[(wg * 64 + n * 16 + rA) * 168 + kc * 32 + kg8];
        po[n] = __builtin_amdgcn_mfma_f32_16x16x32_bf16(av, pfrag, po[n], 0, 0, 0);
      }
    }
    int q = qt * 16 + rA;
    int s = s0 + q;
    int rb = (lane >> 4) * 4;
    #pragma unroll
    for (int n = 0; n < 4; ++n) {
      int d0 = wg * 64 + n * 16 + rb;
      *(float4*)&ctx_c[hb + (size_t)s * HDIM + d0] =
          make_float4(po[n][0], po[n][1], po[n][2], po[n][3]);
    }
  }
}

// ---------------- local windowed attention (MFMA) + merge -> merged bf16
__global__ __launch_bounds__(256) void k_lattn(const u16* __restrict__ q_bf, const u16* __restrict__ lk_bf,
                                               const u16* __restrict__ lv_t, const float* __restrict__ ctx_c,
                                               u16* __restrict__ merged) {
  __shared__ __align__(16) u16 kv[21760];
  __shared__ __align__(16) float sc[32][164];
  __shared__ __align__(16) u16 pb[32][168];
  int tid = threadIdx.x, lane = tid & 63, wave = tid >> 6;
  int h = blockIdx.y, s0 = blockIdx.x * 32;
  int tbase = s0 - 128;
  const size_t hb = (size_t)h * S_LEN * HDIM;
  int rA = lane & 15, kg8 = (lane >> 4) * 8;
  int qt = wave & 1, wg = wave >> 1;

  short8 aq[4];
  #pragma unroll
  for (int c = 0; c < 4; ++c)
    aq[c] = *(const short8*)&q_bf[hb + (size_t)(s0 + qt * 16 + rA) * HDIM + c * 32 + kg8];

  for (int i = tid; i < 160 * 16; i += 256) {
    int r = i >> 4, cz = (i & 15) * 8;
    int t = tbase + r;
    uint4 val = make_uint4(0, 0, 0, 0);
    if (t >= 0) val = *(const uint4*)&lk_bf[hb + (size_t)t * HDIM + cz];
    *(uint4*)&kv[r * 136 + cz] = val;
  }
  __syncthreads();

  for (int kt = wg; kt < 10; kt += 2) {
    f32x4 a = (f32x4){0.f, 0.f, 0.f, 0.f};
    #pragma unroll
    for (int c = 0; c < 4; ++c) {
      short8 bk2 = *(const short8*)&kv[(kt * 16 + rA) * 136 + c * 32 + kg8];
      a = __builtin_amdgcn_mfma_f32_16x16x32_bf16(aq[c], bk2, a, 0, 0, 0);
    }
    int rq = qt * 16 + (lane >> 4) * 4;
    #pragma unroll
    for (int j = 0; j < 4; ++j) sc[rq + j][kt * 16 + rA] = a[j];
  }
  __syncthreads();

  {
    int ql = tid >> 3, e = tid & 7;
    int ilo = 128 - s0; if (ql > ilo) ilo = ql;
    int ihi = ql + 128;
    float m = -1e30f;
    for (int i = e; i < 160; i += 8) {
      bool valid = (i >= ilo) && (i <= ihi);
      float v = valid ? sc[ql][i] * SCALE : -1e9f;
      sc[ql][i] = v;
      m = fmaxf(m, v);
    }
    m = fmaxf(m, __shfl_xor(m, 1));
    m = fmaxf(m, __shfl_xor(m, 2));
    m = fmaxf(m, __shfl_xor(m, 4));
    float sum = 0.f;
    for (int i = e; i < 160; i += 8) {
      float pv = __expf(sc[ql][i] - m);
      sc[ql][i] = pv;
      sum += pv;
    }
    sum += __shfl_xor(sum, 1);
    sum += __shfl_xor(sum, 2);
    sum += __shfl_xor(sum, 4);
    float inv = 1.f / sum;
    for (int i = e; i < 160; i += 8) pb[ql][i] = f2bf(sc[ql][i] * inv);
  }
  __syncthreads();

  {
    int d = tid & 127, c8s = tid >> 7;
    const size_t hbt = (size_t)h * HDIM * S_LEN;
    for (int c8 = c8s; c8 < 20; c8 += 2) {
      int t0 = tbase + c8 * 8;
      uint4 val = make_uint4(0, 0, 0, 0);
      if (t0 >= 0) val = *(const uint4*)&lv_t[hbt + (size_t)d * S_LEN + t0];
      *(uint4*)&kv[d * 168 + c8 * 8] = val;
    }
  }
  __syncthreads();

  {
    f32x4 po[4];
    #pragma unroll
    for (int n = 0; n < 4; ++n) po[n] = (f32x4){0.f, 0.f, 0.f, 0.f};
    #pragma unroll
    for (int kc = 0; kc < 5; ++kc) {
      short8 pfrag = *(const short8*)&pb[qt * 16 + rA][kc * 32 + kg8];
      #pragma unroll
      for (int n = 0; n < 4; ++n) {
        short8 av = *(const short8*)&kv[(wg * 64 + n * 16 + rA) * 168 + kc * 32 + kg8];
        po[n] = __builtin_amdgcn_mfma_f32_16x16x32_bf16(av, pfrag, po[n], 0, 0, 0);
      }
    }
    int q = qt * 16 + rA;
    int s = s0 + q;
    int rb = (lane >> 4) * 4;
    #pragma unroll
    for (int n = 0; n < 4; ++n) {
      int d0 = wg * 64 + n * 16 + rb;
      float4 cc = *(const float4*)&ctx_c[hb + (size_t)s * HDIM + d0];
      ushort4 o;
      o.x = f2bf(0.5f * (po[n][0] + cc.x));
      o.y = f2bf(0.5f * (po[n][1] + cc.y));
      o.z = f2bf(0.5f * (po[n][2] + cc.z));
      o.w = f2bf(0.5f * (po[n][3] + cc.w));
      *(ushort4*)&merged[(size_t)s * HIDN + h * HDIM + d0] = o;
    }
  }
}

extern "C" void kernel_launch(void* const* d_in, const int* in_sizes, int n_in,
                              void* d_out, int out_size, void* d_ws, size_t ws_size,
                              hipStream_t stream) {
  const float* hs     = (const float*)d_in[0];
  const float* Wq     = (const float*)d_in[1];
  const float* bq     = (const float*)d_in[2];
  const float* Wc     = (const float*)d_in[3];
  const float* bc     = (const float*)d_in[4];
  const float* Wk     = (const float*)d_in[5];
  const float* bk     = (const float*)d_in[6];
  const float* Wv     = (const float*)d_in[7];
  const float* bv     = (const float*)d_in[8];
  const float* Wlk    = (const float*)d_in[9];
  const float* blk    = (const float*)d_in[10];
  const float* Wlv    = (const float*)d_in[11];
  const float* blv    = (const float*)d_in[12];
  const float* qn_w   = (const float*)d_in[13];
  const float* kn_w   = (const float*)d_in[14];
  const float* sink_k = (const float*)d_in[15];
  const float* sink_v = (const float*)d_in[16];
  const float* Wo     = (const float*)d_in[17];
  const float* bo     = (const float*)d_in[18];
  float* out = (float*)d_out;

  char* p = (char*)d_ws;
  auto alloc = [&](size_t bytes) {
    char* r = p;
    p += (bytes + 255) & ~(size_t)255;
    return r;
  };
  float* rope_c  = (float*)alloc((size_t)S_LEN * 32 * 4);
  float* rope_s  = (float*)alloc((size_t)S_LEN * 32 * 4);
  u16*   hs_bf   = (u16*)  alloc((size_t)S_LEN * HIDN * 2);
  u16*   Wt3     = (u16*)  alloc((size_t)3 * HIDN * HIDN * 2);
  u16*   Wt_o    = (u16*)  alloc((size_t)HIDN * HIDN * 2);
  u16*   Wkv_t   = (u16*)  alloc((size_t)2 * HDIM * HIDN * 2);
  u16*   ent_bf  = (u16*)  alloc((size_t)256 * HIDN * 2);
  u16*   q_bf    = (u16*)  alloc((size_t)NHEAD * S_LEN * HDIM * 2);
  u16*   lk_bf   = (u16*)  alloc((size_t)NHEAD * S_LEN * HDIM * 2);
  u16*   lv_t    = (u16*)  alloc((size_t)NHEAD * HDIM * S_LEN * 2);
  u16*   ck_bf   = (u16*)  alloc((size_t)NCHNK * HDIM * 2);
  u16*   cv_t    = (u16*)  alloc((size_t)HDIM * NCHNK * 2);
  float* ctx_c   = (float*)alloc((size_t)NHEAD * S_LEN * HDIM * 4);
  u16*   merged  = (u16*)  alloc((size_t)S_LEN * HIDN * 2);
  (void)ws_size; (void)in_sizes; (void)n_in; (void)out_size;

  k_rope_table<<<256, 256, 0, stream>>>(rope_c, rope_s);
  k_cast_hs<<<4096, 256, 0, stream>>>(hs, hs_bf);

  // chunk entries (bf16)
  k_chunk_we<<<NCHNK, 256, 0, stream>>>(hs, Wc, bc, ent_bf);

  // weight transposes
  k_transpose_w<<<dim3(64, 4, 2), dim3(32, 8), 0, stream>>>(Wk, Wv, Wkv_t);
  k_transpose4<<<dim3(64, 64, 4), dim3(32, 8), 0, stream>>>(Wq, Wlk, Wlv, Wo, Wt3, Wt_o);

  // fused q/lk/lv + ck/cv projections (pipelined 256^2)
  k_gemm256<<<193, 512, 0, stream>>>(hs_bf, Wt3, ent_bf, Wkv_t,
                                     bq, blk, blv, bk, bv, qn_w, kn_w,
                                     rope_c, rope_s, q_bf, lk_bf, lv_t, ck_bf, cv_t);

  // attention
  k_cattn<<<dim3(64, NHEAD), 256, 0, stream>>>(q_bf, ck_bf, cv_t, sink_k, sink_v, ctx_c);
  k_lattn<<<dim3(64, NHEAD), 256, 0, stream>>>(q_bf, lk_bf, lv_t, ctx_c, merged);

  // output projection (pipelined 256^2)
  k_gemm_out256<<<64, 512, 0, stream>>>(merged, Wt_o, bo, out);
}

// Round 8
// 241.910 us; speedup vs baseline: 1.1569x; 1.1569x over previous
//
#include <hip/hip_runtime.h>

// HeavilyCompressedAttention on MI355X (gfx950). R8:
//  - revert gemm256 to R6 (BK=64 8-phase, 0-conflict swizzle) and gemm_out to 128^2
//  - k_attn: merged compressed+local attention, no ctx_c round-trip
//  - k_pre: all preprocessing (4 transposes, cast_hs, rope, chunk_we, transpose_w)
//    in one dispatch. 9 dispatches -> 4.

typedef unsigned short u16;
typedef __attribute__((ext_vector_type(8))) short short8;
typedef __attribute__((ext_vector_type(4))) float f32x4;

#define S_LEN 2048
#define HIDN  2048
#define NHEAD 16
#define HDIM  128
#define NCHNK 128
#define NKT   32                      // K tiles of 64 (gemm256)
#define SCALE 0.08838834764831845f   // 1/sqrt(128)

__device__ __forceinline__ float bf2f(u16 h) {
  return __uint_as_float(((unsigned)h) << 16);
}
__device__ __forceinline__ u16 f2bf(float f) {
  unsigned u = __float_as_uint(f);
  unsigned r = (u + 0x7fffu + ((u >> 16) & 1u)) >> 16;
  return (u16)r;
}

typedef __attribute__((address_space(3))) unsigned int lds_uint;
typedef __attribute__((address_space(1))) unsigned int glb_uint;
__device__ __forceinline__ void gl_lds16(const void* g, void* l) {
  __builtin_amdgcn_global_load_lds((glb_uint*)(unsigned long long)g,
                                   (lds_uint*)(unsigned)(unsigned long long)l,
                                   16, 0, 0);
}

// ---------------- fused preprocessing: grid (64,64,6), block (32,8)
//  z 0..3 : transpose+cast Wq/Wlk/Wlv/Wo (f32 2048x2048 -> bf16 transposed)
//  z 4    : cast hs f32 -> bf16 (4096 x 256thr x 4)
//  z 5    : bid<256 rope_table; bid in [256,384) chunk_we; [384,896) transpose_w
__global__ __launch_bounds__(256) void k_pre(
    const float* __restrict__ Wq, const float* __restrict__ Wlk, const float* __restrict__ Wlv,
    const float* __restrict__ Wo, const float* __restrict__ hs,
    const float* __restrict__ Wc, const float* __restrict__ bc,
    const float* __restrict__ Wk, const float* __restrict__ Wv,
    u16* __restrict__ Wt3, u16* __restrict__ Wt_o, u16* __restrict__ hs_bf,
    float* __restrict__ rope_c, float* __restrict__ rope_s,
    u16* __restrict__ entries_bf, u16* __restrict__ Wkv_t) {
  __shared__ float tile[32][33];
  int z = blockIdx.z;
  int tx = threadIdx.x, ty = threadIdx.y;
  int tid = ty * 32 + tx;
  if (z < 4) {
    const float* src = (z == 0) ? Wq : (z == 1) ? Wlk : (z == 2) ? Wlv : Wo;
    u16* dst = (z < 3) ? (Wt3 + (size_t)z * HIDN * HIDN) : Wt_o;
    int k0 = blockIdx.x * 32, n0 = blockIdx.y * 32;
    #pragma unroll
    for (int i = 0; i < 32; i += 8)
      tile[ty + i][tx] = src[(size_t)(k0 + ty + i) * HIDN + (n0 + tx)];
    __syncthreads();
    #pragma unroll
    for (int i = 0; i < 32; i += 8)
      dst[(size_t)(n0 + ty + i) * HIDN + (k0 + tx)] = f2bf(tile[tx][ty + i]);
    return;
  }
  int bid = blockIdx.y * 64 + blockIdx.x;
  if (z == 4) {   // cast_hs
    size_t i4 = ((size_t)bid * 256 + tid) * 4;
    float4 v = *(const float4*)&hs[i4];
    ushort4 o;
    o.x = f2bf(v.x); o.y = f2bf(v.y); o.z = f2bf(v.z); o.w = f2bf(v.w);
    *(ushort4*)&hs_bf[i4] = o;
    return;
  }
  // z == 5
  if (bid < 256) {   // rope table
    int i = bid * 256 + tid;
    int pos = i >> 5, f = i & 31;
    float inv = __expf(-(float)f * (9.210340371976184f / 32.0f));
    float ang = (float)pos * inv;
    rope_c[i] = cosf(ang);
    rope_s[i] = sinf(ang);
    return;
  }
  if (bid < 384) {   // chunk_we, chunk c = bid-256
    __shared__ float red[16][17];
    __shared__ float wgt[16];
    int c = bid - 256;
    int row = tid >> 4, seg = tid & 15;
    const float* hrow = hs + ((size_t)c * 16 + row) * HIDN;
    float p = 0.f;
    #pragma unroll 8
    for (int k = seg * 128; k < seg * 128 + 128; k += 4) {
      float4 hv = *(const float4*)&hrow[k];
      float4 wv = *(const float4*)&Wc[k];
      p += hv.x * wv.x + hv.y * wv.y + hv.z * wv.z + hv.w * wv.w;
    }
    red[row][seg] = p;
    __syncthreads();
    if (tid < 16) {
      float lg = 0.f;
      #pragma unroll
      for (int j = 0; j < 16; ++j) lg += red[tid][j];
      lg += bc[0];
      float m = lg;
      #pragma unroll
      for (int msk = 1; msk <= 8; msk <<= 1) m = fmaxf(m, __shfl_xor(m, msk));
      float ev = __expf(lg - m);
      float sum = ev;
      #pragma unroll
      for (int msk = 1; msk <= 8; msk <<= 1) sum += __shfl_xor(sum, msk);
      wgt[tid] = ev / sum;
    }
    __syncthreads();
    #pragma unroll
    for (int j = 0; j < 8; ++j) {
      int hb = tid + j * 256;
      float acc = 0.f;
      #pragma unroll
      for (int r = 0; r < 16; ++r)
        acc += wgt[r] * hs[((size_t)c * 16 + r) * HIDN + hb];
      entries_bf[(size_t)c * HIDN + hb] = f2bf(acc);
    }
    return;
  }
  if (bid < 896) {   // transpose_w: idx over orig grid (64,4,2)
    int idx = bid - 384;
    int zw = idx >> 8, byw = (idx >> 6) & 3, bxw = idx & 63;
    const float* src = zw ? Wv : Wk;
    u16* dst = Wkv_t + (size_t)zw * HDIM * 2048;
    int k0 = bxw * 32, n0 = byw * 32;
    #pragma unroll
    for (int i = 0; i < 32; i += 8)
      tile[ty + i][tx] = src[(size_t)(k0 + ty + i) * HDIM + (n0 + tx)];
    __syncthreads();
    #pragma unroll
    for (int i = 0; i < 32; i += 8)
      dst[(size_t)(n0 + ty + i) * 2048 + (k0 + tx)] = f2bf(tile[tx][ty + i]);
  }
}

// ---------------- 256x256 8-phase GEMM for q/lk/lv (+ck/cv block 192)  [R6 verified]
__global__ __launch_bounds__(512, 2) void k_gemm256(
    const u16* __restrict__ A, const u16* __restrict__ Wt3,
    const u16* __restrict__ entries_bf, const u16* __restrict__ Wkv_t,
    const float* __restrict__ bq, const float* __restrict__ blk, const float* __restrict__ blv,
    const float* __restrict__ bk, const float* __restrict__ bv,
    const float* __restrict__ qn_w, const float* __restrict__ kn_w,
    const float* __restrict__ rc, const float* __restrict__ rs,
    u16* __restrict__ q_out, u16* __restrict__ lk_out, u16* __restrict__ lv_t,
    u16* __restrict__ ck_bf, u16* __restrict__ cv_t) {
  __shared__ __align__(16) u16 lds[65536];     // 128 KB
  __shared__ float psq[2][4][128];             // 4 KB
  int tid = threadIdx.x, lane = tid & 63;
  int wid = tid >> 6;
  int wr = wid >> 2, wc = wid & 3;             // 2 x 4 waves
  int lin = blockIdx.x;
  int row0, col0, mode;
  const u16 *Ag, *Bg;
  if (lin < 192) {
    int swz = (lin & 7) * 24 + (lin >> 3);     // XCD-bijective 192 = 8*24
    mode = swz >> 6;
    int tile = swz & 63;
    row0 = (tile & 7) * 256;
    col0 = (tile >> 3) * 256;
    Ag = A; Bg = Wt3 + (size_t)mode * HIDN * HIDN;
  } else {
    mode = 3; row0 = 0; col0 = 0;
    Ag = entries_bf; Bg = Wkv_t;
  }
  int rA = lane & 15, kg = lane >> 4;          // kg in [0,4)
  int srow = tid >> 3, sslot = tid & 7;
  int ssl = sslot ^ (srow & 7);                // inverse swizzle on SOURCE slot

  f32x4 acc[8][4];
  #pragma unroll
  for (int m = 0; m < 8; ++m)
    #pragma unroll
    for (int n = 0; n < 4; ++n) acc[m][n] = (f32x4){0.f, 0.f, 0.f, 0.f};

  auto stage = [&](int b, int i, int kt) {
    const u16* src = (i < 4) ? Ag : Bg;
    int rg = ((i < 4) ? row0 : col0) + ((i & 3) * 64) + srow;
    gl_lds16(&src[(size_t)rg * HIDN + kt * 64 + ssl * 8],
             &lds[b * 32768 + i * 4096 + tid * 8]);
  };
  auto rdA = [&](int b, int m, int ks) -> short8 {
    int r = wr * 128 + m * 16 + rA;
    int slot = (ks * 4 + kg) ^ (r & 7);
    return *(const short8*)&lds[b * 32768 + r * 64 + slot * 8];
  };
  auto rdB = [&](int b, int n, int ks) -> short8 {
    int r = wc * 64 + n * 16 + rA;
    int slot = (ks * 4 + kg) ^ (r & 7);
    return *(const short8*)&lds[b * 32768 + 16384 + r * 64 + slot * 8];
  };

  #pragma unroll
  for (int i = 0; i < 8; ++i) stage(0, i, 0);

  short8 Afr[4][2], Bfr[4][2];
  for (int u = 0; u < NKT; ++u) {
    int cur = u & 1;
    asm volatile("s_waitcnt vmcnt(0)" ::: "memory");
    __builtin_amdgcn_sched_barrier(0);
    __builtin_amdgcn_s_barrier();
    bool pf = (u + 1 < NKT);
    // phase 1
    #pragma unroll
    for (int m = 0; m < 4; ++m) { Afr[m][0] = rdA(cur, m, 0); Afr[m][1] = rdA(cur, m, 1); }
    #pragma unroll
    for (int n = 0; n < 2; ++n) { Bfr[n][0] = rdB(cur, n, 0); Bfr[n][1] = rdB(cur, n, 1); }
    if (pf) { stage(cur ^ 1, 0, u + 1); stage(cur ^ 1, 1, u + 1);
              stage(cur ^ 1, 2, u + 1); stage(cur ^ 1, 3, u + 1); }
    __builtin_amdgcn_s_barrier();
    asm volatile("s_waitcnt lgkmcnt(0)" ::: "memory");
    __builtin_amdgcn_sched_barrier(0);
    __builtin_amdgcn_s_setprio(1);
    #pragma unroll
    for (int m = 0; m < 4; ++m)
      #pragma unroll
      for (int n = 0; n < 2; ++n) {
        acc[m][n] = __builtin_amdgcn_mfma_f32_16x16x32_bf16(Afr[m][0], Bfr[n][0], acc[m][n], 0, 0, 0);
        acc[m][n] = __builtin_amdgcn_mfma_f32_16x16x32_bf16(Afr[m][1], Bfr[n][1], acc[m][n], 0, 0, 0);
      }
    __builtin_amdgcn_s_setprio(0);
    __builtin_amdgcn_s_barrier();
    // phase 2
    #pragma unroll
    for (int n = 2; n < 4; ++n) { Bfr[n][0] = rdB(cur, n, 0); Bfr[n][1] = rdB(cur, n, 1); }
    if (pf) { stage(cur ^ 1, 4, u + 1); stage(cur ^ 1, 5, u + 1);
              stage(cur ^ 1, 6, u + 1); stage(cur ^ 1, 7, u + 1); }
    __builtin_amdgcn_s_barrier();
    asm volatile("s_waitcnt lgkmcnt(0)" ::: "memory");
    __builtin_amdgcn_sched_barrier(0);
    __builtin_amdgcn_s_setprio(1);
    #pragma unroll
    for (int m = 0; m < 4; ++m)
      #pragma unroll
      for (int n = 2; n < 4; ++n) {
        acc[m][n] = __builtin_amdgcn_mfma_f32_16x16x32_bf16(Afr[m][0], Bfr[n][0], acc[m][n], 0, 0, 0);
        acc[m][n] = __builtin_amdgcn_mfma_f32_16x16x32_bf16(Afr[m][1], Bfr[n][1], acc[m][n], 0, 0, 0);
      }
    __builtin_amdgcn_s_setprio(0);
    __builtin_amdgcn_s_barrier();
    // phase 3
    #pragma unroll
    for (int m = 0; m < 4; ++m) { Afr[m][0] = rdA(cur, m + 4, 0); Afr[m][1] = rdA(cur, m + 4, 1); }
    __builtin_amdgcn_s_barrier();
    asm volatile("s_waitcnt lgkmcnt(0)" ::: "memory");
    __builtin_amdgcn_sched_barrier(0);
    __builtin_amdgcn_s_setprio(1);
    #pragma unroll
    for (int m = 0; m < 4; ++m)
      #pragma unroll
      for (int n = 2; n < 4; ++n) {
        acc[m + 4][n] = __builtin_amdgcn_mfma_f32_16x16x32_bf16(Afr[m][0], Bfr[n][0], acc[m + 4][n], 0, 0, 0);
        acc[m + 4][n] = __builtin_amdgcn_mfma_f32_16x16x32_bf16(Afr[m][1], Bfr[n][1], acc[m + 4][n], 0, 0, 0);
      }
    __builtin_amdgcn_s_setprio(0);
    __builtin_amdgcn_s_barrier();
    // phase 4
    __builtin_amdgcn_s_setprio(1);
    #pragma unroll
    for (int m = 0; m < 4; ++m)
      #pragma unroll
      for (int n = 0; n < 2; ++n) {
        acc[m + 4][n] = __builtin_amdgcn_mfma_f32_16x16x32_bf16(Afr[m][0], Bfr[n][0], acc[m + 4][n], 0, 0, 0);
        acc[m + 4][n] = __builtin_amdgcn_mfma_f32_16x16x32_bf16(Afr[m][1], Bfr[n][1], acc[m + 4][n], 0, 0, 0);
      }
    __builtin_amdgcn_s_setprio(0);
    __builtin_amdgcn_s_barrier();
  }

  // epilogue
  int cl = rA, rbase = kg * 4;
  #pragma unroll
  for (int n = 0; n < 4; ++n) {
    int dl = wc * 64 + n * 16 + cl;
    float bb;
    if (mode == 3)      bb = (dl < 128) ? bk[dl] : bv[dl - 128];
    else if (mode == 0) bb = bq[col0 + dl];
    else if (mode == 1) bb = blk[col0 + dl];
    else                bb = blv[col0 + dl];
    #pragma unroll
    for (int m = 0; m < 8; ++m)
      #pragma unroll
      for (int j = 0; j < 4; ++j) acc[m][n][j] += bb;
  }

  if (mode == 2) {
    int hh = (col0 >> 7) + (wc >> 1);
    #pragma unroll
    for (int m = 0; m < 8; ++m) {
      int sb = row0 + wr * 128 + m * 16 + rbase;
      #pragma unroll
      for (int n = 0; n < 4; ++n) {
        int dl = (wc & 1) * 64 + n * 16 + cl;
        ushort4 o;
        o.x = f2bf(acc[m][n][0]);
        o.y = f2bf(acc[m][n][1]);
        o.z = f2bf(acc[m][n][2]);
        o.w = f2bf(acc[m][n][3]);
        *(ushort4*)&lv_t[((size_t)hh * HDIM + dl) * S_LEN + sb] = o;
      }
    }
    return;
  }

  bool is_cv = (mode == 3) && (wc >= 2);
  if (!is_cv) {
    #pragma unroll
    for (int m = 0; m < 8; ++m)
      #pragma unroll
      for (int j = 0; j < 4; ++j) {
        float s2 = acc[m][0][j] * acc[m][0][j] + acc[m][1][j] * acc[m][1][j]
                 + acc[m][2][j] * acc[m][2][j] + acc[m][3][j] * acc[m][3][j];
        s2 += __shfl_xor(s2, 1); s2 += __shfl_xor(s2, 2);
        s2 += __shfl_xor(s2, 4); s2 += __shfl_xor(s2, 8);
        if (cl == 0) psq[wr][wc][m * 16 + rbase + j] = s2;
      }
  }
  __syncthreads();
  if (is_cv) {
    if (wr == 0) {
      #pragma unroll
      for (int m = 0; m < 8; ++m) {
        int cchunk = m * 16 + rbase;
        #pragma unroll
        for (int n = 0; n < 4; ++n) {
          int d = (wc - 2) * 64 + n * 16 + cl;
          #pragma unroll
          for (int j = 0; j < 4; ++j)
            cv_t[(size_t)d * NCHNK + cchunk + j] = f2bf(acc[m][n][j]);
        }
      }
    }
    return;
  }
  {
    const float* nw = (mode == 0) ? qn_w : kn_w;
    int hgrp = wc >> 1;
    float nwv[4];
    #pragma unroll
    for (int n = 0; n < 4; ++n) nwv[n] = nw[(wc & 1) * 64 + n * 16 + cl];
    #pragma unroll
    for (int m = 0; m < 8; ++m)
      #pragma unroll
      for (int j = 0; j < 4; ++j) {
        int r16 = m * 16 + rbase + j;
        int s = row0 + wr * 128 + r16;
        bool valid = (mode != 3) || (s < NCHNK);
        int sc2 = valid ? s : 0;
        int pos = (mode == 3) ? (sc2 * 16 + 15) : sc2;
        float rr2 = rsqrtf((psq[wr][hgrp * 2][r16] + psq[wr][hgrp * 2 + 1][r16]) * (1.f / 128.f) + 1e-6f);
        float o[4];
        if ((wc & 1) == 0) {
          #pragma unroll
          for (int n = 0; n < 2; ++n) {
            int i = n * 16 + cl;
            float ca = rc[pos * 32 + i], sa = rs[pos * 32 + i];
            float y1 = acc[m][n][j] * rr2 * nwv[n];
            float y2 = acc[m][n + 2][j] * rr2 * nwv[n + 2];
            o[n] = y1 * ca - y2 * sa;
            o[n + 2] = y1 * sa + y2 * ca;
          }
        } else {
          #pragma unroll
          for (int n = 0; n < 4; ++n) o[n] = acc[m][n][j] * rr2 * nwv[n];
        }
        if (valid) {
          u16* dst;
          if (mode == 3) dst = ck_bf + (size_t)s * HDIM + (wc & 1) * 64;
          else {
            u16* dstb = (mode == 0) ? q_out : lk_out;
            dst = dstb + ((size_t)((col0 >> 7) + hgrp) * S_LEN + s) * HDIM + (wc & 1) * 64;
          }
          #pragma unroll
          for (int n = 0; n < 4; ++n) dst[n * 16 + cl] = f2bf(o[n]);
        }
      }
  }
}

// ---------------- out GEMM: merged(bf16) @ Wt_o^T + bo -> f32, 128^2, XCD swizzle [R6]
__global__ __launch_bounds__(256) void k_gemm_out(const u16* __restrict__ A, const u16* __restrict__ Bt,
                                                  const float* __restrict__ bias, float* __restrict__ C) {
  __shared__ __align__(16) u16 As[128 * 32];
  __shared__ __align__(16) u16 Bs[128 * 32];
  int tid = threadIdx.x, lane = tid & 63, wave = tid >> 6;
  int wr = wave >> 1, wc = wave & 1;
  int lin = blockIdx.x + (blockIdx.y << 4);
  int swz = (lin & 7) * 32 + (lin >> 3);
  int row0 = (swz & 15) * 128, col0 = (swz >> 4) * 128;
  f32x4 acc[4][4];
  #pragma unroll
  for (int m = 0; m < 4; ++m)
    #pragma unroll
    for (int n = 0; n < 4; ++n) acc[m][n] = (f32x4){0.f, 0.f, 0.f, 0.f};
  int r0 = tid >> 2, koff = (tid & 3) * 8;
  int rA = lane & 15, kg = (lane >> 4) * 8;
  for (int k0 = 0; k0 < HIDN; k0 += 32) {
    gl_lds16(&A [(size_t)(row0 + r0)      * HIDN + k0 + koff], &As[tid * 8]);
    gl_lds16(&A [(size_t)(row0 + 64 + r0) * HIDN + k0 + koff], &As[2048 + tid * 8]);
    gl_lds16(&Bt[(size_t)(col0 + r0)      * HIDN + k0 + koff], &Bs[tid * 8]);
    gl_lds16(&Bt[(size_t)(col0 + 64 + r0) * HIDN + k0 + koff], &Bs[2048 + tid * 8]);
    __syncthreads();
    short8 af[4], bfv[4];
    #pragma unroll
    for (int m = 0; m < 4; ++m) af[m]  = *(const short8*)&As[(wr * 64 + m * 16 + rA) * 32 + kg];
    #pragma unroll
    for (int n = 0; n < 4; ++n) bfv[n] = *(const short8*)&Bs[(wc * 64 + n * 16 + rA) * 32 + kg];
    #pragma unroll
    for (int m = 0; m < 4; ++m)
      #pragma unroll
      for (int n = 0; n < 4; ++n)
        acc[m][n] = __builtin_amdgcn_mfma_f32_16x16x32_bf16(af[m], bfv[n], acc[m][n], 0, 0, 0);
    __syncthreads();
  }
  int rbase = (lane >> 4) * 4, cl = lane & 15;
  #pragma unroll
  for (int m = 0; m < 4; ++m) {
    int rowb = row0 + wr * 64 + m * 16 + rbase;
    #pragma unroll
    for (int n = 0; n < 4; ++n) {
      int col = col0 + wc * 64 + n * 16 + cl;
      float bb = bias[col];
      #pragma unroll
      for (int j = 0; j < 4; ++j)
        C[(size_t)(rowb + j) * HIDN + col] = acc[m][n][j] + bb;
    }
  }
}

// ---------------- merged attention: compressed (+sink) then local, merged write
__global__ __launch_bounds__(256) void k_attn(const u16* __restrict__ q_bf, const u16* __restrict__ ck_bf,
                                              const u16* __restrict__ cv_t, const float* __restrict__ sink_k,
                                              const float* __restrict__ sink_v,
                                              const u16* __restrict__ lk_bf, const u16* __restrict__ lv_t,
                                              u16* __restrict__ merged) {
  __shared__ __align__(16) u16 kv[21760];     // K tiles / V^T, reused across phases
  __shared__ __align__(16) float sc[32][164];
  __shared__ __align__(16) u16 pb[32][168];
  int tid = threadIdx.x, lane = tid & 63, wave = tid >> 6;
  int h = blockIdx.y, s0 = blockIdx.x * 32;
  const size_t hb = (size_t)h * S_LEN * HDIM;
  int rA = lane & 15, kg8 = (lane >> 4) * 8;
  int qt = wave & 1, wg = wave >> 1;

  short8 aq[4];
  #pragma unroll
  for (int c = 0; c < 4; ++c)
    aq[c] = *(const short8*)&q_bf[hb + (size_t)(s0 + qt * 16 + rA) * HDIM + c * 32 + kg8];

  // ======== compressed phase ========
  int cmax = s0 / 16 + 2; if (cmax > 128) cmax = 128;
  int nkeys = cmax + 1;
  int nkt = (nkeys + 15) >> 4, nkc = (nkeys + 31) >> 5;

  for (int i = tid; i < cmax * 16; i += 256) {
    int r = i >> 4, cz = (i & 15) * 8;
    *(uint4*)&kv[r * 136 + cz] = *(const uint4*)&ck_bf[r * HDIM + cz];
  }
  if (tid < 128) kv[cmax * 136 + tid] = f2bf(sink_k[h * HDIM + tid]);
  __syncthreads();

  for (int kt = wg; kt < nkt; kt += 2) {
    f32x4 a = (f32x4){0.f, 0.f, 0.f, 0.f};
    #pragma unroll
    for (int c = 0; c < 4; ++c) {
      short8 bk2 = *(const short8*)&kv[(kt * 16 + rA) * 136 + c * 32 + kg8];
      a = __builtin_amdgcn_mfma_f32_16x16x32_bf16(aq[c], bk2, a, 0, 0, 0);
    }
    int rq = qt * 16 + (lane >> 4) * 4;
    #pragma unroll
    for (int j = 0; j < 4; ++j) sc[rq + j][kt * 16 + rA] = a[j];
  }
  __syncthreads();

  { // softmax (8 lanes / row)
    int ql = tid >> 3, e = tid & 7, s = s0 + ql;
    int NK = nkc * 32;
    float m = -1e30f;
    for (int i = e; i < NK; i += 8) {
      if (i < nkeys) {
        float raw = sc[ql][i];
        bool valid = (i < cmax) ? (i * 16 + 15 <= s) : true;
        float v = valid ? raw * SCALE : -1e9f;
        sc[ql][i] = v;
        m = fmaxf(m, v);
      }
    }
    m = fmaxf(m, __shfl_xor(m, 1));
    m = fmaxf(m, __shfl_xor(m, 2));
    m = fmaxf(m, __shfl_xor(m, 4));
    float sum = 0.f;
    for (int i = e; i < NK; i += 8) {
      if (i < nkeys) {
        float pv = __expf(sc[ql][i] - m);
        sc[ql][i] = pv;
        sum += pv;
      }
    }
    sum += __shfl_xor(sum, 1);
    sum += __shfl_xor(sum, 2);
    sum += __shfl_xor(sum, 4);
    float inv = 1.f / sum;
    for (int i = e; i < NK; i += 8)
      pb[ql][i] = (i < nkeys) ? f2bf(sc[ql][i] * inv) : (u16)0;
  }
  __syncthreads();

  { // stage V^T (d x keys); col cmax = sink_v; beyond = 0
    int d = tid & 127, cstart = tid >> 7;
    u16 sv = f2bf(sink_v[h * HDIM + d]);
    int NC = nkc * 32;
    for (int c = cstart; c < NC; c += 2) {
      u16 v = (c < cmax) ? cv_t[(size_t)d * NCHNK + c] : ((c == cmax) ? sv : (u16)0);
      kv[d * 168 + c] = v;
    }
  }
  __syncthreads();

  f32x4 po_c[4];
  #pragma unroll
  for (int n = 0; n < 4; ++n) po_c[n] = (f32x4){0.f, 0.f, 0.f, 0.f};
  for (int kc = 0; kc < nkc; ++kc) {
    short8 pfrag = *(const short8*)&pb[qt * 16 + rA][kc * 32 + kg8];
    #pragma unroll
    for (int n = 0; n < 4; ++n) {
      short8 av = *(const short8*)&kv[(wg * 64 + n * 16 + rA) * 168 + kc * 32 + kg8];
      po_c[n] = __builtin_amdgcn_mfma_f32_16x16x32_bf16(av, pfrag, po_c[n], 0, 0, 0);
    }
  }
  __syncthreads();   // done reading kv/pb; local phase overwrites

  // ======== local phase ========
  int tbase = s0 - 128;
  for (int i = tid; i < 160 * 16; i += 256) {
    int r = i >> 4, cz = (i & 15) * 8;
    int t = tbase + r;
    uint4 val = make_uint4(0, 0, 0, 0);
    if (t >= 0) val = *(const uint4*)&lk_bf[hb + (size_t)t * HDIM + cz];
    *(uint4*)&kv[r * 136 + cz] = val;
  }
  __syncthreads();

  for (int kt = wg; kt < 10; kt += 2) {
    f32x4 a = (f32x4){0.f, 0.f, 0.f, 0.f};
    #pragma unroll
    for (int c = 0; c < 4; ++c) {
      short8 bk2 = *(const short8*)&kv[(kt * 16 + rA) * 136 + c * 32 + kg8];
      a = __builtin_amdgcn_mfma_f32_16x16x32_bf16(aq[c], bk2, a, 0, 0, 0);
    }
    int rq = qt * 16 + (lane >> 4) * 4;
    #pragma unroll
    for (int j = 0; j < 4; ++j) sc[rq + j][kt * 16 + rA] = a[j];
  }
  __syncthreads();

  { // softmax over 160: valid i in [max(ql, 128-s0), ql+128]
    int ql = tid >> 3, e = tid & 7;
    int ilo = 128 - s0; if (ql > ilo) ilo = ql;
    int ihi = ql + 128;
    float m = -1e30f;
    for (int i = e; i < 160; i += 8) {
      bool valid = (i >= ilo) && (i <= ihi);
      float v = valid ? sc[ql][i] * SCALE : -1e9f;
      sc[ql][i] = v;
      m = fmaxf(m, v);
    }
    m = fmaxf(m, __shfl_xor(m, 1));
    m = fmaxf(m, __shfl_xor(m, 2));
    m = fmaxf(m, __shfl_xor(m, 4));
    float sum = 0.f;
    for (int i = e; i < 160; i += 8) {
      float pv = __expf(sc[ql][i] - m);
      sc[ql][i] = pv;
      sum += pv;
    }
    sum += __shfl_xor(sum, 1);
    sum += __shfl_xor(sum, 2);
    sum += __shfl_xor(sum, 4);
    float inv = 1.f / sum;
    for (int i = e; i < 160; i += 8) pb[ql][i] = f2bf(sc[ql][i] * inv);
  }
  __syncthreads();

  { // stage V^T from lv_t (h,d,s)
    int d = tid & 127, c8s = tid >> 7;
    const size_t hbt = (size_t)h * HDIM * S_LEN;
    for (int c8 = c8s; c8 < 20; c8 += 2) {
      int t0 = tbase + c8 * 8;
      uint4 val = make_uint4(0, 0, 0, 0);
      if (t0 >= 0) val = *(const uint4*)&lv_t[hbt + (size_t)d * S_LEN + t0];
      *(uint4*)&kv[d * 168 + c8 * 8] = val;
    }
  }
  __syncthreads();

  { // PV + merge with po_c
    f32x4 po[4];
    #pragma unroll
    for (int n = 0; n < 4; ++n) po[n] = (f32x4){0.f, 0.f, 0.f, 0.f};
    #pragma unroll
    for (int kc = 0; kc < 5; ++kc) {
      short8 pfrag = *(const short8*)&pb[qt * 16 + rA][kc * 32 + kg8];
      #pragma unroll
      for (int n = 0; n < 4; ++n) {
        short8 av = *(const short8*)&kv[(wg * 64 + n * 16 + rA) * 168 + kc * 32 + kg8];
        po[n] = __builtin_amdgcn_mfma_f32_16x16x32_bf16(av, pfrag, po[n], 0, 0, 0);
      }
    }
    int q = qt * 16 + rA;
    int s = s0 + q;
    int rb = (lane >> 4) * 4;
    #pragma unroll
    for (int n = 0; n < 4; ++n) {
      int d0 = wg * 64 + n * 16 + rb;
      ushort4 o;
      o.x = f2bf(0.5f * (po[n][0] + po_c[n][0]));
      o.y = f2bf(0.5f * (po[n][1] + po_c[n][1]));
      o.z = f2bf(0.5f * (po[n][2] + po_c[n][2]));
      o.w = f2bf(0.5f * (po[n][3] + po_c[n][3]));
      *(ushort4*)&merged[(size_t)s * HIDN + h * HDIM + d0] = o;
    }
  }
}

extern "C" void kernel_launch(void* const* d_in, const int* in_sizes, int n_in,
                              void* d_out, int out_size, void* d_ws, size_t ws_size,
                              hipStream_t stream) {
  const float* hs     = (const float*)d_in[0];
  const float* Wq     = (const float*)d_in[1];
  const float* bq     = (const float*)d_in[2];
  const float* Wc     = (const float*)d_in[3];
  const float* bc     = (const float*)d_in[4];
  const float* Wk     = (const float*)d_in[5];
  const float* bk     = (const float*)d_in[6];
  const float* Wv     = (const float*)d_in[7];
  const float* bv     = (const float*)d_in[8];
  const float* Wlk    = (const float*)d_in[9];
  const float* blk    = (const float*)d_in[10];
  const float* Wlv    = (const float*)d_in[11];
  const float* blv    = (const float*)d_in[12];
  const float* qn_w   = (const float*)d_in[13];
  const float* kn_w   = (const float*)d_in[14];
  const float* sink_k = (const float*)d_in[15];
  const float* sink_v = (const float*)d_in[16];
  const float* Wo     = (const float*)d_in[17];
  const float* bo     = (const float*)d_in[18];
  float* out = (float*)d_out;

  char* p = (char*)d_ws;
  auto alloc = [&](size_t bytes) {
    char* r = p;
    p += (bytes + 255) & ~(size_t)255;
    return r;
  };
  float* rope_c  = (float*)alloc((size_t)S_LEN * 32 * 4);
  float* rope_s  = (float*)alloc((size_t)S_LEN * 32 * 4);
  u16*   hs_bf   = (u16*)  alloc((size_t)S_LEN * HIDN * 2);
  u16*   Wt3     = (u16*)  alloc((size_t)3 * HIDN * HIDN * 2);
  u16*   Wt_o    = (u16*)  alloc((size_t)HIDN * HIDN * 2);
  u16*   Wkv_t   = (u16*)  alloc((size_t)2 * HDIM * HIDN * 2);
  u16*   ent_bf  = (u16*)  alloc((size_t)256 * HIDN * 2);
  u16*   q_bf    = (u16*)  alloc((size_t)NHEAD * S_LEN * HDIM * 2);
  u16*   lk_bf   = (u16*)  alloc((size_t)NHEAD * S_LEN * HDIM * 2);
  u16*   lv_t    = (u16*)  alloc((size_t)NHEAD * HDIM * S_LEN * 2);
  u16*   ck_bf   = (u16*)  alloc((size_t)NCHNK * HDIM * 2);
  u16*   cv_t    = (u16*)  alloc((size_t)HDIM * NCHNK * 2);
  u16*   merged  = (u16*)  alloc((size_t)S_LEN * HIDN * 2);
  (void)ws_size; (void)in_sizes; (void)n_in; (void)out_size;

  // all preprocessing in one dispatch
  k_pre<<<dim3(64, 64, 6), dim3(32, 8), 0, stream>>>(Wq, Wlk, Wlv, Wo, hs, Wc, bc, Wk, Wv,
                                                     Wt3, Wt_o, hs_bf, rope_c, rope_s,
                                                     ent_bf, Wkv_t);

  // fused q/lk/lv + ck/cv projections (8-phase 256^2)
  k_gemm256<<<193, 512, 0, stream>>>(hs_bf, Wt3, ent_bf, Wkv_t,
                                     bq, blk, blv, bk, bv, qn_w, kn_w,
                                     rope_c, rope_s, q_bf, lk_bf, lv_t, ck_bf, cv_t);

  // merged attention (compressed + local + merge)
  k_attn<<<dim3(64, NHEAD), 256, 0, stream>>>(q_bf, ck_bf, cv_t, sink_k, sink_v,
                                              lk_bf, lv_t, merged);

  // output projection
  k_gemm_out<<<dim3(16, 16), 256, 0, stream>>>(merged, Wt_o, bo, out);
}

// Round 9
// 223.959 us; speedup vs baseline: 1.2497x; 1.0802x over previous
//
#include <hip/hip_runtime.h>

// HeavilyCompressedAttention on MI355X (gfx950). R9:
//  - k_gemm256: same tile/swizzle/buffers as R6/R8 (BK=64, 2x64KB, ^(r&7) slot
//    swizzle), but K-loop restructured: 1 barrier/tile (was 8), stage all 8
//    half-tiles at tile top, 4 barrier-free compute sub-phases. vmcnt(0) now
//    has a full tile of slack.
//  - k_attn: XCD-chunked block swizzle (2 heads/XCD -> KV L2-resident).
//  - everything else identical to R8 (verified).

typedef unsigned short u16;
typedef __attribute__((ext_vector_type(8))) short short8;
typedef __attribute__((ext_vector_type(4))) float f32x4;

#define S_LEN 2048
#define HIDN  2048
#define NHEAD 16
#define HDIM  128
#define NCHNK 128
#define NKT   32                      // K tiles of 64 (gemm256)
#define SCALE 0.08838834764831845f   // 1/sqrt(128)

__device__ __forceinline__ float bf2f(u16 h) {
  return __uint_as_float(((unsigned)h) << 16);
}
__device__ __forceinline__ u16 f2bf(float f) {
  unsigned u = __float_as_uint(f);
  unsigned r = (u + 0x7fffu + ((u >> 16) & 1u)) >> 16;
  return (u16)r;
}

typedef __attribute__((address_space(3))) unsigned int lds_uint;
typedef __attribute__((address_space(1))) unsigned int glb_uint;
__device__ __forceinline__ void gl_lds16(const void* g, void* l) {
  __builtin_amdgcn_global_load_lds((glb_uint*)(unsigned long long)g,
                                   (lds_uint*)(unsigned)(unsigned long long)l,
                                   16, 0, 0);
}

// ---------------- fused preprocessing: grid (64,64,6), block (32,8)
__global__ __launch_bounds__(256) void k_pre(
    const float* __restrict__ Wq, const float* __restrict__ Wlk, const float* __restrict__ Wlv,
    const float* __restrict__ Wo, const float* __restrict__ hs,
    const float* __restrict__ Wc, const float* __restrict__ bc,
    const float* __restrict__ Wk, const float* __restrict__ Wv,
    u16* __restrict__ Wt3, u16* __restrict__ Wt_o, u16* __restrict__ hs_bf,
    float* __restrict__ rope_c, float* __restrict__ rope_s,
    u16* __restrict__ entries_bf, u16* __restrict__ Wkv_t) {
  __shared__ float tile[32][33];
  int z = blockIdx.z;
  int tx = threadIdx.x, ty = threadIdx.y;
  int tid = ty * 32 + tx;
  if (z < 4) {
    const float* src = (z == 0) ? Wq : (z == 1) ? Wlk : (z == 2) ? Wlv : Wo;
    u16* dst = (z < 3) ? (Wt3 + (size_t)z * HIDN * HIDN) : Wt_o;
    int k0 = blockIdx.x * 32, n0 = blockIdx.y * 32;
    #pragma unroll
    for (int i = 0; i < 32; i += 8)
      tile[ty + i][tx] = src[(size_t)(k0 + ty + i) * HIDN + (n0 + tx)];
    __syncthreads();
    #pragma unroll
    for (int i = 0; i < 32; i += 8)
      dst[(size_t)(n0 + ty + i) * HIDN + (k0 + tx)] = f2bf(tile[tx][ty + i]);
    return;
  }
  int bid = blockIdx.y * 64 + blockIdx.x;
  if (z == 4) {   // cast_hs
    size_t i4 = ((size_t)bid * 256 + tid) * 4;
    float4 v = *(const float4*)&hs[i4];
    ushort4 o;
    o.x = f2bf(v.x); o.y = f2bf(v.y); o.z = f2bf(v.z); o.w = f2bf(v.w);
    *(ushort4*)&hs_bf[i4] = o;
    return;
  }
  // z == 5
  if (bid < 256) {   // rope table
    int i = bid * 256 + tid;
    int pos = i >> 5, f = i & 31;
    float inv = __expf(-(float)f * (9.210340371976184f / 32.0f));
    float ang = (float)pos * inv;
    rope_c[i] = cosf(ang);
    rope_s[i] = sinf(ang);
    return;
  }
  if (bid < 384) {   // chunk_we, chunk c = bid-256
    __shared__ float red[16][17];
    __shared__ float wgt[16];
    int c = bid - 256;
    int row = tid >> 4, seg = tid & 15;
    const float* hrow = hs + ((size_t)c * 16 + row) * HIDN;
    float p = 0.f;
    #pragma unroll 8
    for (int k = seg * 128; k < seg * 128 + 128; k += 4) {
      float4 hv = *(const float4*)&hrow[k];
      float4 wv = *(const float4*)&Wc[k];
      p += hv.x * wv.x + hv.y * wv.y + hv.z * wv.z + hv.w * wv.w;
    }
    red[row][seg] = p;
    __syncthreads();
    if (tid < 16) {
      float lg = 0.f;
      #pragma unroll
      for (int j = 0; j < 16; ++j) lg += red[tid][j];
      lg += bc[0];
      float m = lg;
      #pragma unroll
      for (int msk = 1; msk <= 8; msk <<= 1) m = fmaxf(m, __shfl_xor(m, msk));
      float ev = __expf(lg - m);
      float sum = ev;
      #pragma unroll
      for (int msk = 1; msk <= 8; msk <<= 1) sum += __shfl_xor(sum, msk);
      wgt[tid] = ev / sum;
    }
    __syncthreads();
    #pragma unroll
    for (int j = 0; j < 8; ++j) {
      int hb = tid + j * 256;
      float acc = 0.f;
      #pragma unroll
      for (int r = 0; r < 16; ++r)
        acc += wgt[r] * hs[((size_t)c * 16 + r) * HIDN + hb];
      entries_bf[(size_t)c * HIDN + hb] = f2bf(acc);
    }
    return;
  }
  if (bid < 896) {   // transpose_w
    int idx = bid - 384;
    int zw = idx >> 8, byw = (idx >> 6) & 3, bxw = idx & 63;
    const float* src = zw ? Wv : Wk;
    u16* dst = Wkv_t + (size_t)zw * HDIM * 2048;
    int k0 = bxw * 32, n0 = byw * 32;
    #pragma unroll
    for (int i = 0; i < 32; i += 8)
      tile[ty + i][tx] = src[(size_t)(k0 + ty + i) * HDIM + (n0 + tx)];
    __syncthreads();
    #pragma unroll
    for (int i = 0; i < 32; i += 8)
      dst[(size_t)(n0 + ty + i) * 2048 + (k0 + tx)] = f2bf(tile[tx][ty + i]);
  }
}

// ---------------- 256x256 GEMM for q/lk/lv (+ck/cv block 192), 1-barrier pipelined
__global__ __launch_bounds__(512, 2) void k_gemm256(
    const u16* __restrict__ A, const u16* __restrict__ Wt3,
    const u16* __restrict__ entries_bf, const u16* __restrict__ Wkv_t,
    const float* __restrict__ bq, const float* __restrict__ blk, const float* __restrict__ blv,
    const float* __restrict__ bk, const float* __restrict__ bv,
    const float* __restrict__ qn_w, const float* __restrict__ kn_w,
    const float* __restrict__ rc, const float* __restrict__ rs,
    u16* __restrict__ q_out, u16* __restrict__ lk_out, u16* __restrict__ lv_t,
    u16* __restrict__ ck_bf, u16* __restrict__ cv_t) {
  __shared__ __align__(16) u16 lds[65536];     // 128 KB: 2 x 64 KB
  __shared__ float psq[2][4][128];             // 4 KB
  int tid = threadIdx.x, lane = tid & 63;
  int wid = tid >> 6;
  int wr = wid >> 2, wc = wid & 3;             // 2 x 4 waves
  int lin = blockIdx.x;
  int row0, col0, mode;
  const u16 *Ag, *Bg;
  if (lin < 192) {
    int swz = (lin & 7) * 24 + (lin >> 3);     // XCD-bijective 192 = 8*24
    mode = swz >> 6;
    int tile = swz & 63;
    row0 = (tile & 7) * 256;
    col0 = (tile >> 3) * 256;
    Ag = A; Bg = Wt3 + (size_t)mode * HIDN * HIDN;
  } else {
    mode = 3; row0 = 0; col0 = 0;
    Ag = entries_bf; Bg = Wkv_t;
  }
  int rA = lane & 15, kg = lane >> 4;          // kg in [0,4)
  int srow = tid >> 3, sslot = tid & 7;
  int ssl = sslot ^ (srow & 7);                // inverse swizzle on SOURCE slot

  f32x4 acc[8][4];
  #pragma unroll
  for (int m = 0; m < 8; ++m)
    #pragma unroll
    for (int n = 0; n < 4; ++n) acc[m][n] = (f32x4){0.f, 0.f, 0.f, 0.f};

  auto stage = [&](int b, int i, int kt) {
    const u16* src = (i < 4) ? Ag : Bg;
    int rg = ((i < 4) ? row0 : col0) + ((i & 3) * 64) + srow;
    gl_lds16(&src[(size_t)rg * HIDN + kt * 64 + ssl * 8],
             &lds[b * 32768 + i * 4096 + tid * 8]);
  };
  auto rdA = [&](int b, int m, int ks) -> short8 {
    int r = wr * 128 + m * 16 + rA;
    int slot = (ks * 4 + kg) ^ (r & 7);
    return *(const short8*)&lds[b * 32768 + r * 64 + slot * 8];
  };
  auto rdB = [&](int b, int n, int ks) -> short8 {
    int r = wc * 64 + n * 16 + rA;
    int slot = (ks * 4 + kg) ^ (r & 7);
    return *(const short8*)&lds[b * 32768 + 16384 + r * 64 + slot * 8];
  };

  // prologue: tile 0 -> buf 0
  #pragma unroll
  for (int i = 0; i < 8; ++i) stage(0, i, 0);

  short8 Af[4], Bf[4][2];
  for (int u = 0; u < NKT; ++u) {
    int cur = u & 1;
    // buf cur's loads done; all waves finished reading buf cur^1 last tile
    asm volatile("s_waitcnt vmcnt(0)" ::: "memory");
    __builtin_amdgcn_sched_barrier(0);
    __builtin_amdgcn_s_barrier();
    if (u + 1 < NKT) {   // stage next tile into the buffer everyone just released
      #pragma unroll
      for (int i = 0; i < 8; ++i) stage(cur ^ 1, i, u + 1);
    }
    // B fragments resident across sub-phases
    #pragma unroll
    for (int n = 0; n < 4; ++n) { Bf[n][0] = rdB(cur, n, 0); Bf[n][1] = rdB(cur, n, 1); }
    // sub-phase 1: A m0-3 ks0
    #pragma unroll
    for (int m = 0; m < 4; ++m) Af[m] = rdA(cur, m, 0);
    asm volatile("s_waitcnt lgkmcnt(0)" ::: "memory");
    __builtin_amdgcn_sched_barrier(0);
    __builtin_amdgcn_s_setprio(1);
    #pragma unroll
    for (int m = 0; m < 4; ++m)
      #pragma unroll
      for (int n = 0; n < 4; ++n)
        acc[m][n] = __builtin_amdgcn_mfma_f32_16x16x32_bf16(Af[m], Bf[n][0], acc[m][n], 0, 0, 0);
    __builtin_amdgcn_s_setprio(0);
    // sub-phase 2: A m0-3 ks1
    #pragma unroll
    for (int m = 0; m < 4; ++m) Af[m] = rdA(cur, m, 1);
    asm volatile("s_waitcnt lgkmcnt(0)" ::: "memory");
    __builtin_amdgcn_sched_barrier(0);
    __builtin_amdgcn_s_setprio(1);
    #pragma unroll
    for (int m = 0; m < 4; ++m)
      #pragma unroll
      for (int n = 0; n < 4; ++n)
        acc[m][n] = __builtin_amdgcn_mfma_f32_16x16x32_bf16(Af[m], Bf[n][1], acc[m][n], 0, 0, 0);
    __builtin_amdgcn_s_setprio(0);
    // sub-phase 3: A m4-7 ks0
    #pragma unroll
    for (int m = 0; m < 4; ++m) Af[m] = rdA(cur, m + 4, 0);
    asm volatile("s_waitcnt lgkmcnt(0)" ::: "memory");
    __builtin_amdgcn_sched_barrier(0);
    __builtin_amdgcn_s_setprio(1);
    #pragma unroll
    for (int m = 0; m < 4; ++m)
      #pragma unroll
      for (int n = 0; n < 4; ++n)
        acc[m + 4][n] = __builtin_amdgcn_mfma_f32_16x16x32_bf16(Af[m], Bf[n][0], acc[m + 4][n], 0, 0, 0);
    __builtin_amdgcn_s_setprio(0);
    // sub-phase 4: A m4-7 ks1
    #pragma unroll
    for (int m = 0; m < 4; ++m) Af[m] = rdA(cur, m + 4, 1);
    asm volatile("s_waitcnt lgkmcnt(0)" ::: "memory");
    __builtin_amdgcn_sched_barrier(0);
    __builtin_amdgcn_s_setprio(1);
    #pragma unroll
    for (int m = 0; m < 4; ++m)
      #pragma unroll
      for (int n = 0; n < 4; ++n)
        acc[m + 4][n] = __builtin_amdgcn_mfma_f32_16x16x32_bf16(Af[m], Bf[n][1], acc[m + 4][n], 0, 0, 0);
    __builtin_amdgcn_s_setprio(0);
  }

  // ---------------- epilogue (identical to R8)
  int cl = rA, rbase = kg * 4;
  #pragma unroll
  for (int n = 0; n < 4; ++n) {
    int dl = wc * 64 + n * 16 + cl;
    float bb;
    if (mode == 3)      bb = (dl < 128) ? bk[dl] : bv[dl - 128];
    else if (mode == 0) bb = bq[col0 + dl];
    else if (mode == 1) bb = blk[col0 + dl];
    else                bb = blv[col0 + dl];
    #pragma unroll
    for (int m = 0; m < 8; ++m)
      #pragma unroll
      for (int j = 0; j < 4; ++j) acc[m][n][j] += bb;
  }

  if (mode == 2) {
    int hh = (col0 >> 7) + (wc >> 1);
    #pragma unroll
    for (int m = 0; m < 8; ++m) {
      int sb = row0 + wr * 128 + m * 16 + rbase;
      #pragma unroll
      for (int n = 0; n < 4; ++n) {
        int dl = (wc & 1) * 64 + n * 16 + cl;
        ushort4 o;
        o.x = f2bf(acc[m][n][0]);
        o.y = f2bf(acc[m][n][1]);
        o.z = f2bf(acc[m][n][2]);
        o.w = f2bf(acc[m][n][3]);
        *(ushort4*)&lv_t[((size_t)hh * HDIM + dl) * S_LEN + sb] = o;
      }
    }
    return;
  }

  bool is_cv = (mode == 3) && (wc >= 2);
  if (!is_cv) {
    #pragma unroll
    for (int m = 0; m < 8; ++m)
      #pragma unroll
      for (int j = 0; j < 4; ++j) {
        float s2 = acc[m][0][j] * acc[m][0][j] + acc[m][1][j] * acc[m][1][j]
                 + acc[m][2][j] * acc[m][2][j] + acc[m][3][j] * acc[m][3][j];
        s2 += __shfl_xor(s2, 1); s2 += __shfl_xor(s2, 2);
        s2 += __shfl_xor(s2, 4); s2 += __shfl_xor(s2, 8);
        if (cl == 0) psq[wr][wc][m * 16 + rbase + j] = s2;
      }
  }
  __syncthreads();
  if (is_cv) {
    if (wr == 0) {
      #pragma unroll
      for (int m = 0; m < 8; ++m) {
        int cchunk = m * 16 + rbase;
        #pragma unroll
        for (int n = 0; n < 4; ++n) {
          int d = (wc - 2) * 64 + n * 16 + cl;
          #pragma unroll
          for (int j = 0; j < 4; ++j)
            cv_t[(size_t)d * NCHNK + cchunk + j] = f2bf(acc[m][n][j]);
        }
      }
    }
    return;
  }
  {
    const float* nw = (mode == 0) ? qn_w : kn_w;
    int hgrp = wc >> 1;
    float nwv[4];
    #pragma unroll
    for (int n = 0; n < 4; ++n) nwv[n] = nw[(wc & 1) * 64 + n * 16 + cl];
    #pragma unroll
    for (int m = 0; m < 8; ++m)
      #pragma unroll
      for (int j = 0; j < 4; ++j) {
        int r16 = m * 16 + rbase + j;
        int s = row0 + wr * 128 + r16;
        bool valid = (mode != 3) || (s < NCHNK);
        int sc2 = valid ? s : 0;
        int pos = (mode == 3) ? (sc2 * 16 + 15) : sc2;
        float rr2 = rsqrtf((psq[wr][hgrp * 2][r16] + psq[wr][hgrp * 2 + 1][r16]) * (1.f / 128.f) + 1e-6f);
        float o[4];
        if ((wc & 1) == 0) {
          #pragma unroll
          for (int n = 0; n < 2; ++n) {
            int i = n * 16 + cl;
            float ca = rc[pos * 32 + i], sa = rs[pos * 32 + i];
            float y1 = acc[m][n][j] * rr2 * nwv[n];
            float y2 = acc[m][n + 2][j] * rr2 * nwv[n + 2];
            o[n] = y1 * ca - y2 * sa;
            o[n + 2] = y1 * sa + y2 * ca;
          }
        } else {
          #pragma unroll
          for (int n = 0; n < 4; ++n) o[n] = acc[m][n][j] * rr2 * nwv[n];
        }
        if (valid) {
          u16* dst;
          if (mode == 3) dst = ck_bf + (size_t)s * HDIM + (wc & 1) * 64;
          else {
            u16* dstb = (mode == 0) ? q_out : lk_out;
            dst = dstb + ((size_t)((col0 >> 7) + hgrp) * S_LEN + s) * HDIM + (wc & 1) * 64;
          }
          #pragma unroll
          for (int n = 0; n < 4; ++n) dst[n * 16 + cl] = f2bf(o[n]);
        }
      }
  }
}

// ---------------- out GEMM: merged(bf16) @ Wt_o^T + bo -> f32, 128^2, XCD swizzle
__global__ __launch_bounds__(256) void k_gemm_out(const u16* __restrict__ A, const u16* __restrict__ Bt,
                                                  const float* __restrict__ bias, float* __restrict__ C) {
  __shared__ __align__(16) u16 As[128 * 32];
  __shared__ __align__(16) u16 Bs[128 * 32];
  int tid = threadIdx.x, lane = tid & 63, wave = tid >> 6;
  int wr = wave >> 1, wc = wave & 1;
  int lin = blockIdx.x + (blockIdx.y << 4);
  int swz = (lin & 7) * 32 + (lin >> 3);
  int row0 = (swz & 15) * 128, col0 = (swz >> 4) * 128;
  f32x4 acc[4][4];
  #pragma unroll
  for (int m = 0; m < 4; ++m)
    #pragma unroll
    for (int n = 0; n < 4; ++n) acc[m][n] = (f32x4){0.f, 0.f, 0.f, 0.f};
  int r0 = tid >> 2, koff = (tid & 3) * 8;
  int rA = lane & 15, kg = (lane >> 4) * 8;
  for (int k0 = 0; k0 < HIDN; k0 += 32) {
    gl_lds16(&A [(size_t)(row0 + r0)      * HIDN + k0 + koff], &As[tid * 8]);
    gl_lds16(&A [(size_t)(row0 + 64 + r0) * HIDN + k0 + koff], &As[2048 + tid * 8]);
    gl_lds16(&Bt[(size_t)(col0 + r0)      * HIDN + k0 + koff], &Bs[tid * 8]);
    gl_lds16(&Bt[(size_t)(col0 + 64 + r0) * HIDN + k0 + koff], &Bs[2048 + tid * 8]);
    __syncthreads();
    short8 af[4], bfv[4];
    #pragma unroll
    for (int m = 0; m < 4; ++m) af[m]  = *(const short8*)&As[(wr * 64 + m * 16 + rA) * 32 + kg];
    #pragma unroll
    for (int n = 0; n < 4; ++n) bfv[n] = *(const short8*)&Bs[(wc * 64 + n * 16 + rA) * 32 + kg];
    #pragma unroll
    for (int m = 0; m < 4; ++m)
      #pragma unroll
      for (int n = 0; n < 4; ++n)
        acc[m][n] = __builtin_amdgcn_mfma_f32_16x16x32_bf16(af[m], bfv[n], acc[m][n], 0, 0, 0);
    __syncthreads();
  }
  int rbase = (lane >> 4) * 4, cl = lane & 15;
  #pragma unroll
  for (int m = 0; m < 4; ++m) {
    int rowb = row0 + wr * 64 + m * 16 + rbase;
    #pragma unroll
    for (int n = 0; n < 4; ++n) {
      int col = col0 + wc * 64 + n * 16 + cl;
      float bb = bias[col];
      #pragma unroll
      for (int j = 0; j < 4; ++j)
        C[(size_t)(rowb + j) * HIDN + col] = acc[m][n][j] + bb;
    }
  }
}

// ---------------- merged attention: compressed (+sink) then local, merged write
__global__ __launch_bounds__(256) void k_attn(const u16* __restrict__ q_bf, const u16* __restrict__ ck_bf,
                                              const u16* __restrict__ cv_t, const float* __restrict__ sink_k,
                                              const float* __restrict__ sink_v,
                                              const u16* __restrict__ lk_bf, const u16* __restrict__ lv_t,
                                              u16* __restrict__ merged) {
  __shared__ __align__(16) u16 kv[21760];
  __shared__ __align__(16) float sc[32][164];
  __shared__ __align__(16) u16 pb[32][168];
  int tid = threadIdx.x, lane = tid & 63, wave = tid >> 6;
  // XCD-chunked swizzle over 1024 blocks: each XCD gets 2 heads' worth
  int lin = blockIdx.x;
  int sw = (lin & 7) * 128 + (lin >> 3);
  int s0 = (sw & 63) * 32, h = sw >> 6;
  const size_t hb = (size_t)h * S_LEN * HDIM;
  int rA = lane & 15, kg8 = (lane >> 4) * 8;
  int qt = wave & 1, wg = wave >> 1;

  short8 aq[4];
  #pragma unroll
  for (int c = 0; c < 4; ++c)
    aq[c] = *(const short8*)&q_bf[hb + (size_t)(s0 + qt * 16 + rA) * HDIM + c * 32 + kg8];

  // ======== compressed phase ========
  int cmax = s0 / 16 + 2; if (cmax > 128) cmax = 128;
  int nkeys = cmax + 1;
  int nkt = (nkeys + 15) >> 4, nkc = (nkeys + 31) >> 5;

  for (int i = tid; i < cmax * 16; i += 256) {
    int r = i >> 4, cz = (i & 15) * 8;
    *(uint4*)&kv[r * 136 + cz] = *(const uint4*)&ck_bf[r * HDIM + cz];
  }
  if (tid < 128) kv[cmax * 136 + tid] = f2bf(sink_k[h * HDIM + tid]);
  __syncthreads();

  for (int kt = wg; kt < nkt; kt += 2) {
    f32x4 a = (f32x4){0.f, 0.f, 0.f, 0.f};
    #pragma unroll
    for (int c = 0; c < 4; ++c) {
      short8 bk2 = *(const short8*)&kv[(kt * 16 + rA) * 136 + c * 32 + kg8];
      a = __builtin_amdgcn_mfma_f32_16x16x32_bf16(aq[c], bk2, a, 0, 0, 0);
    }
    int rq = qt * 16 + (lane >> 4) * 4;
    #pragma unroll
    for (int j = 0; j < 4; ++j) sc[rq + j][kt * 16 + rA] = a[j];
  }
  __syncthreads();

  { // softmax (8 lanes / row)
    int ql = tid >> 3, e = tid & 7, s = s0 + ql;
    int NK = nkc * 32;
    float m = -1e30f;
    for (int i = e; i < NK; i += 8) {
      if (i < nkeys) {
        float raw = sc[ql][i];
        bool valid = (i < cmax) ? (i * 16 + 15 <= s) : true;
        float v = valid ? raw * SCALE : -1e9f;
        sc[ql][i] = v;
        m = fmaxf(m, v);
      }
    }
    m = fmaxf(m, __shfl_xor(m, 1));
    m = fmaxf(m, __shfl_xor(m, 2));
    m = fmaxf(m, __shfl_xor(m, 4));
    float sum = 0.f;
    for (int i = e; i < NK; i += 8) {
      if (i < nkeys) {
        float pv = __expf(sc[ql][i] - m);
        sc[ql][i] = pv;
        sum += pv;
      }
    }
    sum += __shfl_xor(sum, 1);
    sum += __shfl_xor(sum, 2);
    sum += __shfl_xor(sum, 4);
    float inv = 1.f / sum;
    for (int i = e; i < NK; i += 8)
      pb[ql][i] = (i < nkeys) ? f2bf(sc[ql][i] * inv) : (u16)0;
  }
  __syncthreads();

  { // stage V^T (d x keys); col cmax = sink_v; beyond = 0
    int d = tid & 127, cstart = tid >> 7;
    u16 sv = f2bf(sink_v[h * HDIM + d]);
    int NC = nkc * 32;
    for (int c = cstart; c < NC; c += 2) {
      u16 v = (c < cmax) ? cv_t[(size_t)d * NCHNK + c] : ((c == cmax) ? sv : (u16)0);
      kv[d * 168 + c] = v;
    }
  }
  __syncthreads();

  f32x4 po_c[4];
  #pragma unroll
  for (int n = 0; n < 4; ++n) po_c[n] = (f32x4){0.f, 0.f, 0.f, 0.f};
  for (int kc = 0; kc < nkc; ++kc) {
    short8 pfrag = *(const short8*)&pb[qt * 16 + rA][kc * 32 + kg8];
    #pragma unroll
    for (int n = 0; n < 4; ++n) {
      short8 av = *(const short8*)&kv[(wg * 64 + n * 16 + rA) * 168 + kc * 32 + kg8];
      po_c[n] = __builtin_amdgcn_mfma_f32_16x16x32_bf16(av, pfrag, po_c[n], 0, 0, 0);
    }
  }
  __syncthreads();

  // ======== local phase ========
  int tbase = s0 - 128;
  for (int i = tid; i < 160 * 16; i += 256) {
    int r = i >> 4, cz = (i & 15) * 8;
    int t = tbase + r;
    uint4 val = make_uint4(0, 0, 0, 0);
    if (t >= 0) val = *(const uint4*)&lk_bf[hb + (size_t)t * HDIM + cz];
    *(uint4*)&kv[r * 136 + cz] = val;
  }
  __syncthreads();

  for (int kt = wg; kt < 10; kt += 2) {
    f32x4 a = (f32x4){0.f, 0.f, 0.f, 0.f};
    #pragma unroll
    for (int c = 0; c < 4; ++c) {
      short8 bk2 = *(const short8*)&kv[(kt * 16 + rA) * 136 + c * 32 + kg8];
      a = __builtin_amdgcn_mfma_f32_16x16x32_bf16(aq[c], bk2, a, 0, 0, 0);
    }
    int rq = qt * 16 + (lane >> 4) * 4;
    #pragma unroll
    for (int j = 0; j < 4; ++j) sc[rq + j][kt * 16 + rA] = a[j];
  }
  __syncthreads();

  {
    int ql = tid >> 3, e = tid & 7;
    int ilo = 128 - s0; if (ql > ilo) ilo = ql;
    int ihi = ql + 128;
    float m = -1e30f;
    for (int i = e; i < 160; i += 8) {
      bool valid = (i >= ilo) && (i <= ihi);
      float v = valid ? sc[ql][i] * SCALE : -1e9f;
      sc[ql][i] = v;
      m = fmaxf(m, v);
    }
    m = fmaxf(m, __shfl_xor(m, 1));
    m = fmaxf(m, __shfl_xor(m, 2));
    m = fmaxf(m, __shfl_xor(m, 4));
    float sum = 0.f;
    for (int i = e; i < 160; i += 8) {
      float pv = __expf(sc[ql][i] - m);
      sc[ql][i] = pv;
      sum += pv;
    }
    sum += __shfl_xor(sum, 1);
    sum += __shfl_xor(sum, 2);
    sum += __shfl_xor(sum, 4);
    float inv = 1.f / sum;
    for (int i = e; i < 160; i += 8) pb[ql][i] = f2bf(sc[ql][i] * inv);
  }
  __syncthreads();

  {
    int d = tid & 127, c8s = tid >> 7;
    const size_t hbt = (size_t)h * HDIM * S_LEN;
    for (int c8 = c8s; c8 < 20; c8 += 2) {
      int t0 = tbase + c8 * 8;
      uint4 val = make_uint4(0, 0, 0, 0);
      if (t0 >= 0) val = *(const uint4*)&lv_t[hbt + (size_t)d * S_LEN + t0];
      *(uint4*)&kv[d * 168 + c8 * 8] = val;
    }
  }
  __syncthreads();

  {
    f32x4 po[4];
    #pragma unroll
    for (int n = 0; n < 4; ++n) po[n] = (f32x4){0.f, 0.f, 0.f, 0.f};
    #pragma unroll
    for (int kc = 0; kc < 5; ++kc) {
      short8 pfrag = *(const short8*)&pb[qt * 16 + rA][kc * 32 + kg8];
      #pragma unroll
      for (int n = 0; n < 4; ++n) {
        short8 av = *(const short8*)&kv[(wg * 64 + n * 16 + rA) * 168 + kc * 32 + kg8];
        po[n] = __builtin_amdgcn_mfma_f32_16x16x32_bf16(av, pfrag, po[n], 0, 0, 0);
      }
    }
    int q = qt * 16 + rA;
    int s = s0 + q;
    int rb = (lane >> 4) * 4;
    #pragma unroll
    for (int n = 0; n < 4; ++n) {
      int d0 = wg * 64 + n * 16 + rb;
      ushort4 o;
      o.x = f2bf(0.5f * (po[n][0] + po_c[n][0]));
      o.y = f2bf(0.5f * (po[n][1] + po_c[n][1]));
      o.z = f2bf(0.5f * (po[n][2] + po_c[n][2]));
      o.w = f2bf(0.5f * (po[n][3] + po_c[n][3]));
      *(ushort4*)&merged[(size_t)s * HIDN + h * HDIM + d0] = o;
    }
  }
}

extern "C" void kernel_launch(void* const* d_in, const int* in_sizes, int n_in,
                              void* d_out, int out_size, void* d_ws, size_t ws_size,
                              hipStream_t stream) {
  const float* hs     = (const float*)d_in[0];
  const float* Wq     = (const float*)d_in[1];
  const float* bq     = (const float*)d_in[2];
  const float* Wc     = (const float*)d_in[3];
  const float* bc     = (const float*)d_in[4];
  const float* Wk     = (const float*)d_in[5];
  const float* bk     = (const float*)d_in[6];
  const float* Wv     = (const float*)d_in[7];
  const float* bv     = (const float*)d_in[8];
  const float* Wlk    = (const float*)d_in[9];
  const float* blk    = (const float*)d_in[10];
  const float* Wlv    = (const float*)d_in[11];
  const float* blv    = (const float*)d_in[12];
  const float* qn_w   = (const float*)d_in[13];
  const float* kn_w   = (const float*)d_in[14];
  const float* sink_k = (const float*)d_in[15];
  const float* sink_v = (const float*)d_in[16];
  const float* Wo     = (const float*)d_in[17];
  const float* bo     = (const float*)d_in[18];
  float* out = (float*)d_out;

  char* p = (char*)d_ws;
  auto alloc = [&](size_t bytes) {
    char* r = p;
    p += (bytes + 255) & ~(size_t)255;
    return r;
  };
  float* rope_c  = (float*)alloc((size_t)S_LEN * 32 * 4);
  float* rope_s  = (float*)alloc((size_t)S_LEN * 32 * 4);
  u16*   hs_bf   = (u16*)  alloc((size_t)S_LEN * HIDN * 2);
  u16*   Wt3     = (u16*)  alloc((size_t)3 * HIDN * HIDN * 2);
  u16*   Wt_o    = (u16*)  alloc((size_t)HIDN * HIDN * 2);
  u16*   Wkv_t   = (u16*)  alloc((size_t)2 * HDIM * HIDN * 2);
  u16*   ent_bf  = (u16*)  alloc((size_t)256 * HIDN * 2);
  u16*   q_bf    = (u16*)  alloc((size_t)NHEAD * S_LEN * HDIM * 2);
  u16*   lk_bf   = (u16*)  alloc((size_t)NHEAD * S_LEN * HDIM * 2);
  u16*   lv_t    = (u16*)  alloc((size_t)NHEAD * HDIM * S_LEN * 2);
  u16*   ck_bf   = (u16*)  alloc((size_t)NCHNK * HDIM * 2);
  u16*   cv_t    = (u16*)  alloc((size_t)HDIM * NCHNK * 2);
  u16*   merged  = (u16*)  alloc((size_t)S_LEN * HIDN * 2);
  (void)ws_size; (void)in_sizes; (void)n_in; (void)out_size;

  // all preprocessing in one dispatch
  k_pre<<<dim3(64, 64, 6), dim3(32, 8), 0, stream>>>(Wq, Wlk, Wlv, Wo, hs, Wc, bc, Wk, Wv,
                                                     Wt3, Wt_o, hs_bf, rope_c, rope_s,
                                                     ent_bf, Wkv_t);

  // fused q/lk/lv + ck/cv projections (1-barrier pipelined 256^2)
  k_gemm256<<<193, 512, 0, stream>>>(hs_bf, Wt3, ent_bf, Wkv_t,
                                     bq, blk, blv, bk, bv, qn_w, kn_w,
                                     rope_c, rope_s, q_bf, lk_bf, lv_t, ck_bf, cv_t);

  // merged attention (compressed + local + merge), XCD-chunked
  k_attn<<<1024, 256, 0, stream>>>(q_bf, ck_bf, cv_t, sink_k, sink_v,
                                   lk_bf, lv_t, merged);

  // output projection
  k_gemm_out<<<dim3(16, 16), 256, 0, stream>>>(merged, Wt_o, bo, out);
}

// Round 10
// 216.217 us; speedup vs baseline: 1.2944x; 1.0358x over previous
//
#include <hip/hip_runtime.h>

// HeavilyCompressedAttention on MI355X (gfx950). R10:
//  - k_gemm256: counted-vmcnt 2-buffer pipeline (issue order B,B,B,B,Alow,Alow,
//    Ahigh,Ahigh; vmcnt(10) before m0-3 phases, vmcnt(8) before m4-7) with the
//    verified BK=64 ^(r&7) zero-conflict swizzle. 3 barriers/tile.
//  - k_gemm_out: pipelined 128^2 (same counted structure, 1-deep), 64KB LDS ->
//    2 blocks/CU.
//  - k_pre / k_attn identical to R9 (verified).

typedef unsigned short u16;
typedef __attribute__((ext_vector_type(8))) short short8;
typedef __attribute__((ext_vector_type(4))) float f32x4;

#define S_LEN 2048
#define HIDN  2048
#define NHEAD 16
#define HDIM  128
#define NCHNK 128
#define NKT   32                      // K tiles of 64
#define SCALE 0.08838834764831845f   // 1/sqrt(128)

__device__ __forceinline__ float bf2f(u16 h) {
  return __uint_as_float(((unsigned)h) << 16);
}
__device__ __forceinline__ u16 f2bf(float f) {
  unsigned u = __float_as_uint(f);
  unsigned r = (u + 0x7fffu + ((u >> 16) & 1u)) >> 16;
  return (u16)r;
}

typedef __attribute__((address_space(3))) unsigned int lds_uint;
typedef __attribute__((address_space(1))) unsigned int glb_uint;
__device__ __forceinline__ void gl_lds16(const void* g, void* l) {
  __builtin_amdgcn_global_load_lds((glb_uint*)(unsigned long long)g,
                                   (lds_uint*)(unsigned)(unsigned long long)l,
                                   16, 0, 0);
}

// ---------------- fused preprocessing: grid (64,64,6), block (32,8)
__global__ __launch_bounds__(256) void k_pre(
    const float* __restrict__ Wq, const float* __restrict__ Wlk, const float* __restrict__ Wlv,
    const float* __restrict__ Wo, const float* __restrict__ hs,
    const float* __restrict__ Wc, const float* __restrict__ bc,
    const float* __restrict__ Wk, const float* __restrict__ Wv,
    u16* __restrict__ Wt3, u16* __restrict__ Wt_o, u16* __restrict__ hs_bf,
    float* __restrict__ rope_c, float* __restrict__ rope_s,
    u16* __restrict__ entries_bf, u16* __restrict__ Wkv_t) {
  __shared__ float tile[32][33];
  int z = blockIdx.z;
  int tx = threadIdx.x, ty = threadIdx.y;
  int tid = ty * 32 + tx;
  if (z < 4) {
    const float* src = (z == 0) ? Wq : (z == 1) ? Wlk : (z == 2) ? Wlv : Wo;
    u16* dst = (z < 3) ? (Wt3 + (size_t)z * HIDN * HIDN) : Wt_o;
    int k0 = blockIdx.x * 32, n0 = blockIdx.y * 32;
    #pragma unroll
    for (int i = 0; i < 32; i += 8)
      tile[ty + i][tx] = src[(size_t)(k0 + ty + i) * HIDN + (n0 + tx)];
    __syncthreads();
    #pragma unroll
    for (int i = 0; i < 32; i += 8)
      dst[(size_t)(n0 + ty + i) * HIDN + (k0 + tx)] = f2bf(tile[tx][ty + i]);
    return;
  }
  int bid = blockIdx.y * 64 + blockIdx.x;
  if (z == 4) {   // cast_hs
    size_t i4 = ((size_t)bid * 256 + tid) * 4;
    float4 v = *(const float4*)&hs[i4];
    ushort4 o;
    o.x = f2bf(v.x); o.y = f2bf(v.y); o.z = f2bf(v.z); o.w = f2bf(v.w);
    *(ushort4*)&hs_bf[i4] = o;
    return;
  }
  // z == 5
  if (bid < 256) {   // rope table
    int i = bid * 256 + tid;
    int pos = i >> 5, f = i & 31;
    float inv = __expf(-(float)f * (9.210340371976184f / 32.0f));
    float ang = (float)pos * inv;
    rope_c[i] = cosf(ang);
    rope_s[i] = sinf(ang);
    return;
  }
  if (bid < 384) {   // chunk_we, chunk c = bid-256
    __shared__ float red[16][17];
    __shared__ float wgt[16];
    int c = bid - 256;
    int row = tid >> 4, seg = tid & 15;
    const float* hrow = hs + ((size_t)c * 16 + row) * HIDN;
    float p = 0.f;
    #pragma unroll 8
    for (int k = seg * 128; k < seg * 128 + 128; k += 4) {
      float4 hv = *(const float4*)&hrow[k];
      float4 wv = *(const float4*)&Wc[k];
      p += hv.x * wv.x + hv.y * wv.y + hv.z * wv.z + hv.w * wv.w;
    }
    red[row][seg] = p;
    __syncthreads();
    if (tid < 16) {
      float lg = 0.f;
      #pragma unroll
      for (int j = 0; j < 16; ++j) lg += red[tid][j];
      lg += bc[0];
      float m = lg;
      #pragma unroll
      for (int msk = 1; msk <= 8; msk <<= 1) m = fmaxf(m, __shfl_xor(m, msk));
      float ev = __expf(lg - m);
      float sum = ev;
      #pragma unroll
      for (int msk = 1; msk <= 8; msk <<= 1) sum += __shfl_xor(sum, msk);
      wgt[tid] = ev / sum;
    }
    __syncthreads();
    #pragma unroll
    for (int j = 0; j < 8; ++j) {
      int hb = tid + j * 256;
      float acc = 0.f;
      #pragma unroll
      for (int r = 0; r < 16; ++r)
        acc += wgt[r] * hs[((size_t)c * 16 + r) * HIDN + hb];
      entries_bf[(size_t)c * HIDN + hb] = f2bf(acc);
    }
    return;
  }
  if (bid < 896) {   // transpose_w
    int idx = bid - 384;
    int zw = idx >> 8, byw = (idx >> 6) & 3, bxw = idx & 63;
    const float* src = zw ? Wv : Wk;
    u16* dst = Wkv_t + (size_t)zw * HDIM * 2048;
    int k0 = bxw * 32, n0 = byw * 32;
    #pragma unroll
    for (int i = 0; i < 32; i += 8)
      tile[ty + i][tx] = src[(size_t)(k0 + ty + i) * HDIM + (n0 + tx)];
    __syncthreads();
    #pragma unroll
    for (int i = 0; i < 32; i += 8)
      dst[(size_t)(n0 + ty + i) * 2048 + (k0 + tx)] = f2bf(tile[tx][ty + i]);
  }
}

// ---------------- 256x256 GEMM for q/lk/lv (+ck/cv block 192), counted-vmcnt pipeline
__global__ __launch_bounds__(512, 2) void k_gemm256(
    const u16* __restrict__ A, const u16* __restrict__ Wt3,
    const u16* __restrict__ entries_bf, const u16* __restrict__ Wkv_t,
    const float* __restrict__ bq, const float* __restrict__ blk, const float* __restrict__ blv,
    const float* __restrict__ bk, const float* __restrict__ bv,
    const float* __restrict__ qn_w, const float* __restrict__ kn_w,
    const float* __restrict__ rc, const float* __restrict__ rs,
    u16* __restrict__ q_out, u16* __restrict__ lk_out, u16* __restrict__ lv_t,
    u16* __restrict__ ck_bf, u16* __restrict__ cv_t) {
  __shared__ __align__(16) u16 lds[65536];     // 128 KB: 2 x 64 KB
  __shared__ float psq[2][4][128];             // 4 KB
  int tid = threadIdx.x, lane = tid & 63;
  int wid = tid >> 6;
  int wr = wid >> 2, wc = wid & 3;             // 2 x 4 waves
  int lin = blockIdx.x;
  int row0, col0, mode;
  const u16 *Ag, *Bg;
  if (lin < 192) {
    int swz = (lin & 7) * 24 + (lin >> 3);     // XCD-bijective 192 = 8*24
    mode = swz >> 6;
    int tile = swz & 63;
    row0 = (tile & 7) * 256;
    col0 = (tile >> 3) * 256;
    Ag = A; Bg = Wt3 + (size_t)mode * HIDN * HIDN;
  } else {
    mode = 3; row0 = 0; col0 = 0;
    Ag = entries_bf; Bg = Wkv_t;
  }
  int rA = lane & 15, kg = lane >> 4;          // kg in [0,4)
  int srow = tid >> 3, sslot = tid & 7;
  int ssl = sslot ^ (srow & 7);                // inverse swizzle on SOURCE slot

  f32x4 acc[8][4];
  #pragma unroll
  for (int m = 0; m < 8; ++m)
    #pragma unroll
    for (int n = 0; n < 4; ++n) acc[m][n] = (f32x4){0.f, 0.f, 0.f, 0.f};

  // issue order i=0..7: B halves 0-3 (rows col0+i*64), then A halves in the order
  // the compute consumes them: rows 0-63, 128-191 (m0-3 for wr=0/1), then 64-127, 192-255.
  auto stage = [&](int b, int i, int kt) {
    int ah;     // A half index in row space
    const u16* src;
    int rg, dofs;
    if (i < 4) { src = Bg; rg = col0 + i * 64 + srow; dofs = 16384 + i * 4096; }
    else {
      ah = (i == 4) ? 0 : (i == 5) ? 2 : (i == 6) ? 1 : 3;
      src = Ag; rg = row0 + ah * 64 + srow; dofs = ah * 4096;
    }
    gl_lds16(&src[(size_t)rg * HIDN + kt * 64 + ssl * 8],
             &lds[b * 32768 + dofs + tid * 8]);
  };
  auto rdA = [&](int b, int m, int ks) -> short8 {
    int r = wr * 128 + m * 16 + rA;
    int slot = (ks * 4 + kg) ^ (r & 7);
    return *(const short8*)&lds[b * 32768 + r * 64 + slot * 8];
  };
  auto rdB = [&](int b, int n, int ks) -> short8 {
    int r = wc * 64 + n * 16 + rA;
    int slot = (ks * 4 + kg) ^ (r & 7);
    return *(const short8*)&lds[b * 32768 + 16384 + r * 64 + slot * 8];
  };

  // prologue: tile 0 -> buf 0
  #pragma unroll
  for (int i = 0; i < 8; ++i) stage(0, i, 0);

  short8 Af[4], Bf[4][2];
  for (int u = 0; u < NKT; ++u) {
    int cur = u & 1;
    bool pf = (u + 1 < NKT);
    // buf cur^1 fully read (end-of-tile barrier of u-1) -> issue next tile now
    if (pf) {
      #pragma unroll
      for (int i = 0; i < 8; ++i) stage(cur ^ 1, i, u + 1);
    }
    // need tile-u's first 6 halves (B all + A rows 0-63,128-191)
    if (pf) asm volatile("s_waitcnt vmcnt(10)" ::: "memory");
    else    asm volatile("s_waitcnt vmcnt(2)" ::: "memory");
    __builtin_amdgcn_sched_barrier(0);
    __builtin_amdgcn_s_barrier();
    // B fragments resident across sub-phases
    #pragma unroll
    for (int n = 0; n < 4; ++n) { Bf[n][0] = rdB(cur, n, 0); Bf[n][1] = rdB(cur, n, 1); }
    // sub-phase 1: A m0-3 ks0
    #pragma unroll
    for (int m = 0; m < 4; ++m) Af[m] = rdA(cur, m, 0);
    asm volatile("s_waitcnt lgkmcnt(0)" ::: "memory");
    __builtin_amdgcn_sched_barrier(0);
    __builtin_amdgcn_s_setprio(1);
    #pragma unroll
    for (int m = 0; m < 4; ++m)
      #pragma unroll
      for (int n = 0; n < 4; ++n)
        acc[m][n] = __builtin_amdgcn_mfma_f32_16x16x32_bf16(Af[m], Bf[n][0], acc[m][n], 0, 0, 0);
    __builtin_amdgcn_s_setprio(0);
    // sub-phase 2: A m0-3 ks1
    #pragma unroll
    for (int m = 0; m < 4; ++m) Af[m] = rdA(cur, m, 1);
    asm volatile("s_waitcnt lgkmcnt(0)" ::: "memory");
    __builtin_amdgcn_sched_barrier(0);
    __builtin_amdgcn_s_setprio(1);
    #pragma unroll
    for (int m = 0; m < 4; ++m)
      #pragma unroll
      for (int n = 0; n < 4; ++n)
        acc[m][n] = __builtin_amdgcn_mfma_f32_16x16x32_bf16(Af[m], Bf[n][1], acc[m][n], 0, 0, 0);
    __builtin_amdgcn_s_setprio(0);
    // need tile-u's last 2 halves (A rows 64-127, 192-255)
    if (pf) asm volatile("s_waitcnt vmcnt(8)" ::: "memory");
    else    asm volatile("s_waitcnt vmcnt(0)" ::: "memory");
    __builtin_amdgcn_sched_barrier(0);
    __builtin_amdgcn_s_barrier();
    // sub-phase 3: A m4-7 ks0
    #pragma unroll
    for (int m = 0; m < 4; ++m) Af[m] = rdA(cur, m + 4, 0);
    asm volatile("s_waitcnt lgkmcnt(0)" ::: "memory");
    __builtin_amdgcn_sched_barrier(0);
    __builtin_amdgcn_s_setprio(1);
    #pragma unroll
    for (int m = 0; m < 4; ++m)
      #pragma unroll
      for (int n = 0; n < 4; ++n)
        acc[m + 4][n] = __builtin_amdgcn_mfma_f32_16x16x32_bf16(Af[m], Bf[n][0], acc[m + 4][n], 0, 0, 0);
    __builtin_amdgcn_s_setprio(0);
    // sub-phase 4: A m4-7 ks1
    #pragma unroll
    for (int m = 0; m < 4; ++m) Af[m] = rdA(cur, m + 4, 1);
    asm volatile("s_waitcnt lgkmcnt(0)" ::: "memory");
    __builtin_amdgcn_sched_barrier(0);
    __builtin_amdgcn_s_setprio(1);
    #pragma unroll
    for (int m = 0; m < 4; ++m)
      #pragma unroll
      for (int n = 0; n < 4; ++n)
        acc[m + 4][n] = __builtin_amdgcn_mfma_f32_16x16x32_bf16(Af[m], Bf[n][1], acc[m + 4][n], 0, 0, 0);
    __builtin_amdgcn_s_setprio(0);
    __builtin_amdgcn_s_barrier();   // end-of-tile: buf cur fully read
  }

  // ---------------- epilogue (identical to R9)
  int cl = rA, rbase = kg * 4;
  #pragma unroll
  for (int n = 0; n < 4; ++n) {
    int dl = wc * 64 + n * 16 + cl;
    float bb;
    if (mode == 3)      bb = (dl < 128) ? bk[dl] : bv[dl - 128];
    else if (mode == 0) bb = bq[col0 + dl];
    else if (mode == 1) bb = blk[col0 + dl];
    else                bb = blv[col0 + dl];
    #pragma unroll
    for (int m = 0; m < 8; ++m)
      #pragma unroll
      for (int j = 0; j < 4; ++j) acc[m][n][j] += bb;
  }

  if (mode == 2) {
    int hh = (col0 >> 7) + (wc >> 1);
    #pragma unroll
    for (int m = 0; m < 8; ++m) {
      int sb = row0 + wr * 128 + m * 16 + rbase;
      #pragma unroll
      for (int n = 0; n < 4; ++n) {
        int dl = (wc & 1) * 64 + n * 16 + cl;
        ushort4 o;
        o.x = f2bf(acc[m][n][0]);
        o.y = f2bf(acc[m][n][1]);
        o.z = f2bf(acc[m][n][2]);
        o.w = f2bf(acc[m][n][3]);
        *(ushort4*)&lv_t[((size_t)hh * HDIM + dl) * S_LEN + sb] = o;
      }
    }
    return;
  }

  bool is_cv = (mode == 3) && (wc >= 2);
  if (!is_cv) {
    #pragma unroll
    for (int m = 0; m < 8; ++m)
      #pragma unroll
      for (int j = 0; j < 4; ++j) {
        float s2 = acc[m][0][j] * acc[m][0][j] + acc[m][1][j] * acc[m][1][j]
                 + acc[m][2][j] * acc[m][2][j] + acc[m][3][j] * acc[m][3][j];
        s2 += __shfl_xor(s2, 1); s2 += __shfl_xor(s2, 2);
        s2 += __shfl_xor(s2, 4); s2 += __shfl_xor(s2, 8);
        if (cl == 0) psq[wr][wc][m * 16 + rbase + j] = s2;
      }
  }
  __syncthreads();
  if (is_cv) {
    if (wr == 0) {
      #pragma unroll
      for (int m = 0; m < 8; ++m) {
        int cchunk = m * 16 + rbase;
        #pragma unroll
        for (int n = 0; n < 4; ++n) {
          int d = (wc - 2) * 64 + n * 16 + cl;
          #pragma unroll
          for (int j = 0; j < 4; ++j)
            cv_t[(size_t)d * NCHNK + cchunk + j] = f2bf(acc[m][n][j]);
        }
      }
    }
    return;
  }
  {
    const float* nw = (mode == 0) ? qn_w : kn_w;
    int hgrp = wc >> 1;
    float nwv[4];
    #pragma unroll
    for (int n = 0; n < 4; ++n) nwv[n] = nw[(wc & 1) * 64 + n * 16 + cl];
    #pragma unroll
    for (int m = 0; m < 8; ++m)
      #pragma unroll
      for (int j = 0; j < 4; ++j) {
        int r16 = m * 16 + rbase + j;
        int s = row0 + wr * 128 + r16;
        bool valid = (mode != 3) || (s < NCHNK);
        int sc2 = valid ? s : 0;
        int pos = (mode == 3) ? (sc2 * 16 + 15) : sc2;
        float rr2 = rsqrtf((psq[wr][hgrp * 2][r16] + psq[wr][hgrp * 2 + 1][r16]) * (1.f / 128.f) + 1e-6f);
        float o[4];
        if ((wc & 1) == 0) {
          #pragma unroll
          for (int n = 0; n < 2; ++n) {
            int i = n * 16 + cl;
            float ca = rc[pos * 32 + i], sa = rs[pos * 32 + i];
            float y1 = acc[m][n][j] * rr2 * nwv[n];
            float y2 = acc[m][n + 2][j] * rr2 * nwv[n + 2];
            o[n] = y1 * ca - y2 * sa;
            o[n + 2] = y1 * sa + y2 * ca;
          }
        } else {
          #pragma unroll
          for (int n = 0; n < 4; ++n) o[n] = acc[m][n][j] * rr2 * nwv[n];
        }
        if (valid) {
          u16* dst;
          if (mode == 3) dst = ck_bf + (size_t)s * HDIM + (wc & 1) * 64;
          else {
            u16* dstb = (mode == 0) ? q_out : lk_out;
            dst = dstb + ((size_t)((col0 >> 7) + hgrp) * S_LEN + s) * HDIM + (wc & 1) * 64;
          }
          #pragma unroll
          for (int n = 0; n < 4; ++n) dst[n * 16 + cl] = f2bf(o[n]);
        }
      }
  }
}

// ---------------- out GEMM: pipelined 128^2, counted 1-deep, XCD swizzle
__global__ __launch_bounds__(256, 2) void k_gemm_out(const u16* __restrict__ A, const u16* __restrict__ Bt,
                                                     const float* __restrict__ bias, float* __restrict__ C) {
  __shared__ __align__(16) u16 lds[32768];     // 64 KB: 2 x 32 KB
  int tid = threadIdx.x, lane = tid & 63;
  int wave = tid >> 6;
  int wr = wave >> 1, wc = wave & 1;
  int lin = blockIdx.x + (blockIdx.y << 4);
  int swz = (lin & 7) * 32 + (lin >> 3);       // bijective 256 = 8*32
  int row0 = (swz & 15) * 128, col0 = (swz >> 4) * 128;
  int rA = lane & 15, kg = lane >> 4;
  int srow = tid >> 3, sslot = tid & 7;        // srow in [0,32)
  int ssl = sslot ^ (srow & 7);

  f32x4 acc[4][4];
  #pragma unroll
  for (int m = 0; m < 4; ++m)
    #pragma unroll
    for (int n = 0; n < 4; ++n) acc[m][n] = (f32x4){0.f, 0.f, 0.f, 0.f};

  // i 0-3: B 32-row halves; i 4-7: A 32-row halves
  auto stage = [&](int b, int i, int kt) {
    const u16* src = (i < 4) ? Bt : A;
    int rg = ((i < 4) ? col0 : row0) + (i & 3) * 32 + srow;
    int dofs = (i < 4) ? (8192 + i * 2048) : ((i - 4) * 2048);
    gl_lds16(&src[(size_t)rg * HIDN + kt * 64 + ssl * 8],
             &lds[b * 16384 + dofs + tid * 8]);
  };
  auto rdA = [&](int b, int m, int ks) -> short8 {
    int r = wr * 64 + m * 16 + rA;
    int slot = (ks * 4 + kg) ^ (r & 7);
    return *(const short8*)&lds[b * 16384 + r * 64 + slot * 8];
  };
  auto rdB = [&](int b, int n, int ks) -> short8 {
    int r = wc * 64 + n * 16 + rA;
    int slot = (ks * 4 + kg) ^ (r & 7);
    return *(const short8*)&lds[b * 16384 + 8192 + r * 64 + slot * 8];
  };

  #pragma unroll
  for (int i = 0; i < 8; ++i) stage(0, i, 0);

  short8 Af[4], Bf[4][2];
  for (int u = 0; u < NKT; ++u) {
    int cur = u & 1;
    bool pf = (u + 1 < NKT);
    if (pf) {
      #pragma unroll
      for (int i = 0; i < 8; ++i) stage(cur ^ 1, i, u + 1);
    }
    if (pf) asm volatile("s_waitcnt vmcnt(8)" ::: "memory");
    else    asm volatile("s_waitcnt vmcnt(0)" ::: "memory");
    __builtin_amdgcn_sched_barrier(0);
    __builtin_amdgcn_s_barrier();
    #pragma unroll
    for (int n = 0; n < 4; ++n) { Bf[n][0] = rdB(cur, n, 0); Bf[n][1] = rdB(cur, n, 1); }
    #pragma unroll
    for (int m = 0; m < 4; ++m) Af[m] = rdA(cur, m, 0);
    asm volatile("s_waitcnt lgkmcnt(0)" ::: "memory");
    __builtin_amdgcn_sched_barrier(0);
    __builtin_amdgcn_s_setprio(1);
    #pragma unroll
    for (int m = 0; m < 4; ++m)
      #pragma unroll
      for (int n = 0; n < 4; ++n)
        acc[m][n] = __builtin_amdgcn_mfma_f32_16x16x32_bf16(Af[m], Bf[n][0], acc[m][n], 0, 0, 0);
    __builtin_amdgcn_s_setprio(0);
    #pragma unroll
    for (int m = 0; m < 4; ++m) Af[m] = rdA(cur, m, 1);
    asm volatile("s_waitcnt lgkmcnt(0)" ::: "memory");
    __builtin_amdgcn_sched_barrier(0);
    __builtin_amdgcn_s_setprio(1);
    #pragma unroll
    for (int m = 0; m < 4; ++m)
      #pragma unroll
      for (int n = 0; n < 4; ++n)
        acc[m][n] = __builtin_amdgcn_mfma_f32_16x16x32_bf16(Af[m], Bf[n][1], acc[m][n], 0, 0, 0);
    __builtin_amdgcn_s_setprio(0);
    __builtin_amdgcn_s_barrier();
  }

  int rbase = kg * 4, cl = rA;
  #pragma unroll
  for (int m = 0; m < 4; ++m) {
    int rowb = row0 + wr * 64 + m * 16 + rbase;
    #pragma unroll
    for (int n = 0; n < 4; ++n) {
      int col = col0 + wc * 64 + n * 16 + cl;
      float bb = bias[col];
      #pragma unroll
      for (int j = 0; j < 4; ++j)
        C[(size_t)(rowb + j) * HIDN + col] = acc[m][n][j] + bb;
    }
  }
}

// ---------------- merged attention: compressed (+sink) then local, merged write
__global__ __launch_bounds__(256) void k_attn(const u16* __restrict__ q_bf, const u16* __restrict__ ck_bf,
                                              const u16* __restrict__ cv_t, const float* __restrict__ sink_k,
                                              const float* __restrict__ sink_v,
                                              const u16* __restrict__ lk_bf, const u16* __restrict__ lv_t,
                                              u16* __restrict__ merged) {
  __shared__ __align__(16) u16 kv[21760];
  __shared__ __align__(16) float sc[32][164];
  __shared__ __align__(16) u16 pb[32][168];
  int tid = threadIdx.x, lane = tid & 63, wave = tid >> 6;
  int lin = blockIdx.x;
  int sw = (lin & 7) * 128 + (lin >> 3);
  int s0 = (sw & 63) * 32, h = sw >> 6;
  const size_t hb = (size_t)h * S_LEN * HDIM;
  int rA = lane & 15, kg8 = (lane >> 4) * 8;
  int qt = wave & 1, wg = wave >> 1;

  short8 aq[4];
  #pragma unroll
  for (int c = 0; c < 4; ++c)
    aq[c] = *(const short8*)&q_bf[hb + (size_t)(s0 + qt * 16 + rA) * HDIM + c * 32 + kg8];

  // ======== compressed phase ========
  int cmax = s0 / 16 + 2; if (cmax > 128) cmax = 128;
  int nkeys = cmax + 1;
  int nkt = (nkeys + 15) >> 4, nkc = (nkeys + 31) >> 5;

  for (int i = tid; i < cmax * 16; i += 256) {
    int r = i >> 4, cz = (i & 15) * 8;
    *(uint4*)&kv[r * 136 + cz] = *(const uint4*)&ck_bf[r * HDIM + cz];
  }
  if (tid < 128) kv[cmax * 136 + tid] = f2bf(sink_k[h * HDIM + tid]);
  __syncthreads();

  for (int kt = wg; kt < nkt; kt += 2) {
    f32x4 a = (f32x4){0.f, 0.f, 0.f, 0.f};
    #pragma unroll
    for (int c = 0; c < 4; ++c) {
      short8 bk2 = *(const short8*)&kv[(kt * 16 + rA) * 136 + c * 32 + kg8];
      a = __builtin_amdgcn_mfma_f32_16x16x32_bf16(aq[c], bk2, a, 0, 0, 0);
    }
    int rq = qt * 16 + (lane >> 4) * 4;
    #pragma unroll
    for (int j = 0; j < 4; ++j) sc[rq + j][kt * 16 + rA] = a[j];
  }
  __syncthreads();

  { // softmax (8 lanes / row)
    int ql = tid >> 3, e = tid & 7, s = s0 + ql;
    int NK = nkc * 32;
    float m = -1e30f;
    for (int i = e; i < NK; i += 8) {
      if (i < nkeys) {
        float raw = sc[ql][i];
        bool valid = (i < cmax) ? (i * 16 + 15 <= s) : true;
        float v = valid ? raw * SCALE : -1e9f;
        sc[ql][i] = v;
        m = fmaxf(m, v);
      }
    }
    m = fmaxf(m, __shfl_xor(m, 1));
    m = fmaxf(m, __shfl_xor(m, 2));
    m = fmaxf(m, __shfl_xor(m, 4));
    float sum = 0.f;
    for (int i = e; i < NK; i += 8) {
      if (i < nkeys) {
        float pv = __expf(sc[ql][i] - m);
        sc[ql][i] = pv;
        sum += pv;
      }
    }
    sum += __shfl_xor(sum, 1);
    sum += __shfl_xor(sum, 2);
    sum += __shfl_xor(sum, 4);
    float inv = 1.f / sum;
    for (int i = e; i < NK; i += 8)
      pb[ql][i] = (i < nkeys) ? f2bf(sc[ql][i] * inv) : (u16)0;
  }
  __syncthreads();

  { // stage V^T (d x keys); col cmax = sink_v; beyond = 0
    int d = tid & 127, cstart = tid >> 7;
    u16 sv = f2bf(sink_v[h * HDIM + d]);
    int NC = nkc * 32;
    for (int c = cstart; c < NC; c += 2) {
      u16 v = (c < cmax) ? cv_t[(size_t)d * NCHNK + c] : ((c == cmax) ? sv : (u16)0);
      kv[d * 168 + c] = v;
    }
  }
  __syncthreads();

  f32x4 po_c[4];
  #pragma unroll
  for (int n = 0; n < 4; ++n) po_c[n] = (f32x4){0.f, 0.f, 0.f, 0.f};
  for (int kc = 0; kc < nkc; ++kc) {
    short8 pfrag = *(const short8*)&pb[qt * 16 + rA][kc * 32 + kg8];
    #pragma unroll
    for (int n = 0; n < 4; ++n) {
      short8 av = *(const short8*)&kv[(wg * 64 + n * 16 + rA) * 168 + kc * 32 + kg8];
      po_c[n] = __builtin_amdgcn_mfma_f32_16x16x32_bf16(av, pfrag, po_c[n], 0, 0, 0);
    }
  }
  __syncthreads();

  // ======== local phase ========
  int tbase = s0 - 128;
  for (int i = tid; i < 160 * 16; i += 256) {
    int r = i >> 4, cz = (i & 15) * 8;
    int t = tbase + r;
    uint4 val = make_uint4(0, 0, 0, 0);
    if (t >= 0) val = *(const uint4*)&lk_bf[hb + (size_t)t * HDIM + cz];
    *(uint4*)&kv[r * 136 + cz] = val;
  }
  __syncthreads();

  for (int kt = wg; kt < 10; kt += 2) {
    f32x4 a = (f32x4){0.f, 0.f, 0.f, 0.f};
    #pragma unroll
    for (int c = 0; c < 4; ++c) {
      short8 bk2 = *(const short8*)&kv[(kt * 16 + rA) * 136 + c * 32 + kg8];
      a = __builtin_amdgcn_mfma_f32_16x16x32_bf16(aq[c], bk2, a, 0, 0, 0);
    }
    int rq = qt * 16 + (lane >> 4) * 4;
    #pragma unroll
    for (int j = 0; j < 4; ++j) sc[rq + j][kt * 16 + rA] = a[j];
  }
  __syncthreads();

  {
    int ql = tid >> 3, e = tid & 7;
    int ilo = 128 - s0; if (ql > ilo) ilo = ql;
    int ihi = ql + 128;
    float m = -1e30f;
    for (int i = e; i < 160; i += 8) {
      bool valid = (i >= ilo) && (i <= ihi);
      float v = valid ? sc[ql][i] * SCALE : -1e9f;
      sc[ql][i] = v;
      m = fmaxf(m, v);
    }
    m = fmaxf(m, __shfl_xor(m, 1));
    m = fmaxf(m, __shfl_xor(m, 2));
    m = fmaxf(m, __shfl_xor(m, 4));
    float sum = 0.f;
    for (int i = e; i < 160; i += 8) {
      float pv = __expf(sc[ql][i] - m);
      sc[ql][i] = pv;
      sum += pv;
    }
    sum += __shfl_xor(sum, 1);
    sum += __shfl_xor(sum, 2);
    sum += __shfl_xor(sum, 4);
    float inv = 1.f / sum;
    for (int i = e; i < 160; i += 8) pb[ql][i] = f2bf(sc[ql][i] * inv);
  }
  __syncthreads();

  {
    int d = tid & 127, c8s = tid >> 7;
    const size_t hbt = (size_t)h * HDIM * S_LEN;
    for (int c8 = c8s; c8 < 20; c8 += 2) {
      int t0 = tbase + c8 * 8;
      uint4 val = make_uint4(0, 0, 0, 0);
      if (t0 >= 0) val = *(const uint4*)&lv_t[hbt + (size_t)d * S_LEN + t0];
      *(uint4*)&kv[d * 168 + c8 * 8] = val;
    }
  }
  __syncthreads();

  {
    f32x4 po[4];
    #pragma unroll
    for (int n = 0; n < 4; ++n) po[n] = (f32x4){0.f, 0.f, 0.f, 0.f};
    #pragma unroll
    for (int kc = 0; kc < 5; ++kc) {
      short8 pfrag = *(const short8*)&pb[qt * 16 + rA][kc * 32 + kg8];
      #pragma unroll
      for (int n = 0; n < 4; ++n) {
        short8 av = *(const short8*)&kv[(wg * 64 + n * 16 + rA) * 168 + kc * 32 + kg8];
        po[n] = __builtin_amdgcn_mfma_f32_16x16x32_bf16(av, pfrag, po[n], 0, 0, 0);
      }
    }
    int q = qt * 16 + rA;
    int s = s0 + q;
    int rb = (lane >> 4) * 4;
    #pragma unroll
    for (int n = 0; n < 4; ++n) {
      int d0 = wg * 64 + n * 16 + rb;
      ushort4 o;
      o.x = f2bf(0.5f * (po[n][0] + po_c[n][0]));
      o.y = f2bf(0.5f * (po[n][1] + po_c[n][1]));
      o.z = f2bf(0.5f * (po[n][2] + po_c[n][2]));
      o.w = f2bf(0.5f * (po[n][3] + po_c[n][3]));
      *(ushort4*)&merged[(size_t)s * HIDN + h * HDIM + d0] = o;
    }
  }
}

extern "C" void kernel_launch(void* const* d_in, const int* in_sizes, int n_in,
                              void* d_out, int out_size, void* d_ws, size_t ws_size,
                              hipStream_t stream) {
  const float* hs     = (const float*)d_in[0];
  const float* Wq     = (const float*)d_in[1];
  const float* bq     = (const float*)d_in[2];
  const float* Wc     = (const float*)d_in[3];
  const float* bc     = (const float*)d_in[4];
  const float* Wk     = (const float*)d_in[5];
  const float* bk     = (const float*)d_in[6];
  const float* Wv     = (const float*)d_in[7];
  const float* bv     = (const float*)d_in[8];
  const float* Wlk    = (const float*)d_in[9];
  const float* blk    = (const float*)d_in[10];
  const float* Wlv    = (const float*)d_in[11];
  const float* blv    = (const float*)d_in[12];
  const float* qn_w   = (const float*)d_in[13];
  const float* kn_w   = (const float*)d_in[14];
  const float* sink_k = (const float*)d_in[15];
  const float* sink_v = (const float*)d_in[16];
  const float* Wo     = (const float*)d_in[17];
  const float* bo     = (const float*)d_in[18];
  float* out = (float*)d_out;

  char* p = (char*)d_ws;
  auto alloc = [&](size_t bytes) {
    char* r = p;
    p += (bytes + 255) & ~(size_t)255;
    return r;
  };
  float* rope_c  = (float*)alloc((size_t)S_LEN * 32 * 4);
  float* rope_s  = (float*)alloc((size_t)S_LEN * 32 * 4);
  u16*   hs_bf   = (u16*)  alloc((size_t)S_LEN * HIDN * 2);
  u16*   Wt3     = (u16*)  alloc((size_t)3 * HIDN * HIDN * 2);
  u16*   Wt_o    = (u16*)  alloc((size_t)HIDN * HIDN * 2);
  u16*   Wkv_t   = (u16*)  alloc((size_t)2 * HDIM * HIDN * 2);
  u16*   ent_bf  = (u16*)  alloc((size_t)256 * HIDN * 2);
  u16*   q_bf    = (u16*)  alloc((size_t)NHEAD * S_LEN * HDIM * 2);
  u16*   lk_bf   = (u16*)  alloc((size_t)NHEAD * S_LEN * HDIM * 2);
  u16*   lv_t    = (u16*)  alloc((size_t)NHEAD * HDIM * S_LEN * 2);
  u16*   ck_bf   = (u16*)  alloc((size_t)NCHNK * HDIM * 2);
  u16*   cv_t    = (u16*)  alloc((size_t)HDIM * NCHNK * 2);
  u16*   merged  = (u16*)  alloc((size_t)S_LEN * HIDN * 2);
  (void)ws_size; (void)in_sizes; (void)n_in; (void)out_size;

  // all preprocessing in one dispatch
  k_pre<<<dim3(64, 64, 6), dim3(32, 8), 0, stream>>>(Wq, Wlk, Wlv, Wo, hs, Wc, bc, Wk, Wv,
                                                     Wt3, Wt_o, hs_bf, rope_c, rope_s,
                                                     ent_bf, Wkv_t);

  // fused q/lk/lv + ck/cv projections (counted-vmcnt pipelined 256^2)
  k_gemm256<<<193, 512, 0, stream>>>(hs_bf, Wt3, ent_bf, Wkv_t,
                                     bq, blk, blv, bk, bv, qn_w, kn_w,
                                     rope_c, rope_s, q_bf, lk_bf, lv_t, ck_bf, cv_t);

  // merged attention (compressed + local + merge), XCD-chunked
  k_attn<<<1024, 256, 0, stream>>>(q_bf, ck_bf, cv_t, sink_k, sink_v,
                                   lk_bf, lv_t, merged);

  // output projection (pipelined 128^2)
  k_gemm_out<<<dim3(16, 16), 256, 0, stream>>>(merged, Wt_o, bo, out);
}

// Round 11
// 195.731 us; speedup vs baseline: 1.4299x; 1.1047x over previous
//
#include <hip/hip_runtime.h>

// HeavilyCompressedAttention on MI355X (gfx950). R11:
//  - k_gemm256: revert K-loop to R9's verified 1-barrier structure (78.4 us);
//    R10's counted-vmcnt variant regressed (85.5) at 1 block/CU.
//  - k_gemm_out: keep R10's pipelined 128^2 (verified win).
//  - k_attn: vectorized (uint4) compressed V^T staging bulk + scalar tail.
//  - k_pre identical.

typedef unsigned short u16;
typedef __attribute__((ext_vector_type(8))) short short8;
typedef __attribute__((ext_vector_type(4))) float f32x4;

#define S_LEN 2048
#define HIDN  2048
#define NHEAD 16
#define HDIM  128
#define NCHNK 128
#define NKT   32                      // K tiles of 64
#define SCALE 0.08838834764831845f   // 1/sqrt(128)

__device__ __forceinline__ float bf2f(u16 h) {
  return __uint_as_float(((unsigned)h) << 16);
}
__device__ __forceinline__ u16 f2bf(float f) {
  unsigned u = __float_as_uint(f);
  unsigned r = (u + 0x7fffu + ((u >> 16) & 1u)) >> 16;
  return (u16)r;
}

typedef __attribute__((address_space(3))) unsigned int lds_uint;
typedef __attribute__((address_space(1))) unsigned int glb_uint;
__device__ __forceinline__ void gl_lds16(const void* g, void* l) {
  __builtin_amdgcn_global_load_lds((glb_uint*)(unsigned long long)g,
                                   (lds_uint*)(unsigned)(unsigned long long)l,
                                   16, 0, 0);
}

// ---------------- fused preprocessing: grid (64,64,6), block (32,8)
__global__ __launch_bounds__(256) void k_pre(
    const float* __restrict__ Wq, const float* __restrict__ Wlk, const float* __restrict__ Wlv,
    const float* __restrict__ Wo, const float* __restrict__ hs,
    const float* __restrict__ Wc, const float* __restrict__ bc,
    const float* __restrict__ Wk, const float* __restrict__ Wv,
    u16* __restrict__ Wt3, u16* __restrict__ Wt_o, u16* __restrict__ hs_bf,
    float* __restrict__ rope_c, float* __restrict__ rope_s,
    u16* __restrict__ entries_bf, u16* __restrict__ Wkv_t) {
  __shared__ float tile[32][33];
  int z = blockIdx.z;
  int tx = threadIdx.x, ty = threadIdx.y;
  int tid = ty * 32 + tx;
  if (z < 4) {
    const float* src = (z == 0) ? Wq : (z == 1) ? Wlk : (z == 2) ? Wlv : Wo;
    u16* dst = (z < 3) ? (Wt3 + (size_t)z * HIDN * HIDN) : Wt_o;
    int k0 = blockIdx.x * 32, n0 = blockIdx.y * 32;
    #pragma unroll
    for (int i = 0; i < 32; i += 8)
      tile[ty + i][tx] = src[(size_t)(k0 + ty + i) * HIDN + (n0 + tx)];
    __syncthreads();
    #pragma unroll
    for (int i = 0; i < 32; i += 8)
      dst[(size_t)(n0 + ty + i) * HIDN + (k0 + tx)] = f2bf(tile[tx][ty + i]);
    return;
  }
  int bid = blockIdx.y * 64 + blockIdx.x;
  if (z == 4) {   // cast_hs
    size_t i4 = ((size_t)bid * 256 + tid) * 4;
    float4 v = *(const float4*)&hs[i4];
    ushort4 o;
    o.x = f2bf(v.x); o.y = f2bf(v.y); o.z = f2bf(v.z); o.w = f2bf(v.w);
    *(ushort4*)&hs_bf[i4] = o;
    return;
  }
  // z == 5
  if (bid < 256) {   // rope table
    int i = bid * 256 + tid;
    int pos = i >> 5, f = i & 31;
    float inv = __expf(-(float)f * (9.210340371976184f / 32.0f));
    float ang = (float)pos * inv;
    rope_c[i] = cosf(ang);
    rope_s[i] = sinf(ang);
    return;
  }
  if (bid < 384) {   // chunk_we, chunk c = bid-256
    __shared__ float red[16][17];
    __shared__ float wgt[16];
    int c = bid - 256;
    int row = tid >> 4, seg = tid & 15;
    const float* hrow = hs + ((size_t)c * 16 + row) * HIDN;
    float p = 0.f;
    #pragma unroll 8
    for (int k = seg * 128; k < seg * 128 + 128; k += 4) {
      float4 hv = *(const float4*)&hrow[k];
      float4 wv = *(const float4*)&Wc[k];
      p += hv.x * wv.x + hv.y * wv.y + hv.z * wv.z + hv.w * wv.w;
    }
    red[row][seg] = p;
    __syncthreads();
    if (tid < 16) {
      float lg = 0.f;
      #pragma unroll
      for (int j = 0; j < 16; ++j) lg += red[tid][j];
      lg += bc[0];
      float m = lg;
      #pragma unroll
      for (int msk = 1; msk <= 8; msk <<= 1) m = fmaxf(m, __shfl_xor(m, msk));
      float ev = __expf(lg - m);
      float sum = ev;
      #pragma unroll
      for (int msk = 1; msk <= 8; msk <<= 1) sum += __shfl_xor(sum, msk);
      wgt[tid] = ev / sum;
    }
    __syncthreads();
    #pragma unroll
    for (int j = 0; j < 8; ++j) {
      int hb = tid + j * 256;
      float acc = 0.f;
      #pragma unroll
      for (int r = 0; r < 16; ++r)
        acc += wgt[r] * hs[((size_t)c * 16 + r) * HIDN + hb];
      entries_bf[(size_t)c * HIDN + hb] = f2bf(acc);
    }
    return;
  }
  if (bid < 896) {   // transpose_w
    int idx = bid - 384;
    int zw = idx >> 8, byw = (idx >> 6) & 3, bxw = idx & 63;
    const float* src = zw ? Wv : Wk;
    u16* dst = Wkv_t + (size_t)zw * HDIM * 2048;
    int k0 = bxw * 32, n0 = byw * 32;
    #pragma unroll
    for (int i = 0; i < 32; i += 8)
      tile[ty + i][tx] = src[(size_t)(k0 + ty + i) * HDIM + (n0 + tx)];
    __syncthreads();
    #pragma unroll
    for (int i = 0; i < 32; i += 8)
      dst[(size_t)(n0 + ty + i) * 2048 + (k0 + tx)] = f2bf(tile[tx][ty + i]);
  }
}

// ---------------- 256x256 GEMM for q/lk/lv (+ck/cv block 192), R9 1-barrier pipeline
__global__ __launch_bounds__(512, 2) void k_gemm256(
    const u16* __restrict__ A, const u16* __restrict__ Wt3,
    const u16* __restrict__ entries_bf, const u16* __restrict__ Wkv_t,
    const float* __restrict__ bq, const float* __restrict__ blk, const float* __restrict__ blv,
    const float* __restrict__ bk, const float* __restrict__ bv,
    const float* __restrict__ qn_w, const float* __restrict__ kn_w,
    const float* __restrict__ rc, const float* __restrict__ rs,
    u16* __restrict__ q_out, u16* __restrict__ lk_out, u16* __restrict__ lv_t,
    u16* __restrict__ ck_bf, u16* __restrict__ cv_t) {
  __shared__ __align__(16) u16 lds[65536];     // 128 KB: 2 x 64 KB
  __shared__ float psq[2][4][128];             // 4 KB
  int tid = threadIdx.x, lane = tid & 63;
  int wid = tid >> 6;
  int wr = wid >> 2, wc = wid & 3;             // 2 x 4 waves
  int lin = blockIdx.x;
  int row0, col0, mode;
  const u16 *Ag, *Bg;
  if (lin < 192) {
    int swz = (lin & 7) * 24 + (lin >> 3);     // XCD-bijective 192 = 8*24
    mode = swz >> 6;
    int tile = swz & 63;
    row0 = (tile & 7) * 256;
    col0 = (tile >> 3) * 256;
    Ag = A; Bg = Wt3 + (size_t)mode * HIDN * HIDN;
  } else {
    mode = 3; row0 = 0; col0 = 0;
    Ag = entries_bf; Bg = Wkv_t;
  }
  int rA = lane & 15, kg = lane >> 4;          // kg in [0,4)
  int srow = tid >> 3, sslot = tid & 7;
  int ssl = sslot ^ (srow & 7);                // inverse swizzle on SOURCE slot

  f32x4 acc[8][4];
  #pragma unroll
  for (int m = 0; m < 8; ++m)
    #pragma unroll
    for (int n = 0; n < 4; ++n) acc[m][n] = (f32x4){0.f, 0.f, 0.f, 0.f};

  auto stage = [&](int b, int i, int kt) {
    const u16* src = (i < 4) ? Ag : Bg;
    int rg = ((i < 4) ? row0 : col0) + ((i & 3) * 64) + srow;
    gl_lds16(&src[(size_t)rg * HIDN + kt * 64 + ssl * 8],
             &lds[b * 32768 + i * 4096 + tid * 8]);
  };
  auto rdA = [&](int b, int m, int ks) -> short8 {
    int r = wr * 128 + m * 16 + rA;
    int slot = (ks * 4 + kg) ^ (r & 7);
    return *(const short8*)&lds[b * 32768 + r * 64 + slot * 8];
  };
  auto rdB = [&](int b, int n, int ks) -> short8 {
    int r = wc * 64 + n * 16 + rA;
    int slot = (ks * 4 + kg) ^ (r & 7);
    return *(const short8*)&lds[b * 32768 + 16384 + r * 64 + slot * 8];
  };

  // prologue: tile 0 -> buf 0
  #pragma unroll
  for (int i = 0; i < 8; ++i) stage(0, i, 0);

  short8 Af[4], Bf[4][2];
  for (int u = 0; u < NKT; ++u) {
    int cur = u & 1;
    asm volatile("s_waitcnt vmcnt(0)" ::: "memory");
    __builtin_amdgcn_sched_barrier(0);
    __builtin_amdgcn_s_barrier();
    if (u + 1 < NKT) {
      #pragma unroll
      for (int i = 0; i < 8; ++i) stage(cur ^ 1, i, u + 1);
    }
    #pragma unroll
    for (int n = 0; n < 4; ++n) { Bf[n][0] = rdB(cur, n, 0); Bf[n][1] = rdB(cur, n, 1); }
    // sub-phase 1: A m0-3 ks0
    #pragma unroll
    for (int m = 0; m < 4; ++m) Af[m] = rdA(cur, m, 0);
    asm volatile("s_waitcnt lgkmcnt(0)" ::: "memory");
    __builtin_amdgcn_sched_barrier(0);
    __builtin_amdgcn_s_setprio(1);
    #pragma unroll
    for (int m = 0; m < 4; ++m)
      #pragma unroll
      for (int n = 0; n < 4; ++n)
        acc[m][n] = __builtin_amdgcn_mfma_f32_16x16x32_bf16(Af[m], Bf[n][0], acc[m][n], 0, 0, 0);
    __builtin_amdgcn_s_setprio(0);
    // sub-phase 2: A m0-3 ks1
    #pragma unroll
    for (int m = 0; m < 4; ++m) Af[m] = rdA(cur, m, 1);
    asm volatile("s_waitcnt lgkmcnt(0)" ::: "memory");
    __builtin_amdgcn_sched_barrier(0);
    __builtin_amdgcn_s_setprio(1);
    #pragma unroll
    for (int m = 0; m < 4; ++m)
      #pragma unroll
      for (int n = 0; n < 4; ++n)
        acc[m][n] = __builtin_amdgcn_mfma_f32_16x16x32_bf16(Af[m], Bf[n][1], acc[m][n], 0, 0, 0);
    __builtin_amdgcn_s_setprio(0);
    // sub-phase 3: A m4-7 ks0
    #pragma unroll
    for (int m = 0; m < 4; ++m) Af[m] = rdA(cur, m + 4, 0);
    asm volatile("s_waitcnt lgkmcnt(0)" ::: "memory");
    __builtin_amdgcn_sched_barrier(0);
    __builtin_amdgcn_s_setprio(1);
    #pragma unroll
    for (int m = 0; m < 4; ++m)
      #pragma unroll
      for (int n = 0; n < 4; ++n)
        acc[m + 4][n] = __builtin_amdgcn_mfma_f32_16x16x32_bf16(Af[m], Bf[n][0], acc[m + 4][n], 0, 0, 0);
    __builtin_amdgcn_s_setprio(0);
    // sub-phase 4: A m4-7 ks1
    #pragma unroll
    for (int m = 0; m < 4; ++m) Af[m] = rdA(cur, m + 4, 1);
    asm volatile("s_waitcnt lgkmcnt(0)" ::: "memory");
    __builtin_amdgcn_sched_barrier(0);
    __builtin_amdgcn_s_setprio(1);
    #pragma unroll
    for (int m = 0; m < 4; ++m)
      #pragma unroll
      for (int n = 0; n < 4; ++n)
        acc[m + 4][n] = __builtin_amdgcn_mfma_f32_16x16x32_bf16(Af[m], Bf[n][1], acc[m + 4][n], 0, 0, 0);
    __builtin_amdgcn_s_setprio(0);
  }

  // ---------------- epilogue
  int cl = rA, rbase = kg * 4;
  #pragma unroll
  for (int n = 0; n < 4; ++n) {
    int dl = wc * 64 + n * 16 + cl;
    float bb;
    if (mode == 3)      bb = (dl < 128) ? bk[dl] : bv[dl - 128];
    else if (mode == 0) bb = bq[col0 + dl];
    else if (mode == 1) bb = blk[col0 + dl];
    else                bb = blv[col0 + dl];
    #pragma unroll
    for (int m = 0; m < 8; ++m)
      #pragma unroll
      for (int j = 0; j < 4; ++j) acc[m][n][j] += bb;
  }

  if (mode == 2) {
    int hh = (col0 >> 7) + (wc >> 1);
    #pragma unroll
    for (int m = 0; m < 8; ++m) {
      int sb = row0 + wr * 128 + m * 16 + rbase;
      #pragma unroll
      for (int n = 0; n < 4; ++n) {
        int dl = (wc & 1) * 64 + n * 16 + cl;
        ushort4 o;
        o.x = f2bf(acc[m][n][0]);
        o.y = f2bf(acc[m][n][1]);
        o.z = f2bf(acc[m][n][2]);
        o.w = f2bf(acc[m][n][3]);
        *(ushort4*)&lv_t[((size_t)hh * HDIM + dl) * S_LEN + sb] = o;
      }
    }
    return;
  }

  bool is_cv = (mode == 3) && (wc >= 2);
  if (!is_cv) {
    #pragma unroll
    for (int m = 0; m < 8; ++m)
      #pragma unroll
      for (int j = 0; j < 4; ++j) {
        float s2 = acc[m][0][j] * acc[m][0][j] + acc[m][1][j] * acc[m][1][j]
                 + acc[m][2][j] * acc[m][2][j] + acc[m][3][j] * acc[m][3][j];
        s2 += __shfl_xor(s2, 1); s2 += __shfl_xor(s2, 2);
        s2 += __shfl_xor(s2, 4); s2 += __shfl_xor(s2, 8);
        if (cl == 0) psq[wr][wc][m * 16 + rbase + j] = s2;
      }
  }
  __syncthreads();
  if (is_cv) {
    if (wr == 0) {
      #pragma unroll
      for (int m = 0; m < 8; ++m) {
        int cchunk = m * 16 + rbase;
        #pragma unroll
        for (int n = 0; n < 4; ++n) {
          int d = (wc - 2) * 64 + n * 16 + cl;
          #pragma unroll
          for (int j = 0; j < 4; ++j)
            cv_t[(size_t)d * NCHNK + cchunk + j] = f2bf(acc[m][n][j]);
        }
      }
    }
    return;
  }
  {
    const float* nw = (mode == 0) ? qn_w : kn_w;
    int hgrp = wc >> 1;
    float nwv[4];
    #pragma unroll
    for (int n = 0; n < 4; ++n) nwv[n] = nw[(wc & 1) * 64 + n * 16 + cl];
    #pragma unroll
    for (int m = 0; m < 8; ++m)
      #pragma unroll
      for (int j = 0; j < 4; ++j) {
        int r16 = m * 16 + rbase + j;
        int s = row0 + wr * 128 + r16;
        bool valid = (mode != 3) || (s < NCHNK);
        int sc2 = valid ? s : 0;
        int pos = (mode == 3) ? (sc2 * 16 + 15) : sc2;
        float rr2 = rsqrtf((psq[wr][hgrp * 2][r16] + psq[wr][hgrp * 2 + 1][r16]) * (1.f / 128.f) + 1e-6f);
        float o[4];
        if ((wc & 1) == 0) {
          #pragma unroll
          for (int n = 0; n < 2; ++n) {
            int i = n * 16 + cl;
            float ca = rc[pos * 32 + i], sa = rs[pos * 32 + i];
            float y1 = acc[m][n][j] * rr2 * nwv[n];
            float y2 = acc[m][n + 2][j] * rr2 * nwv[n + 2];
            o[n] = y1 * ca - y2 * sa;
            o[n + 2] = y1 * sa + y2 * ca;
          }
        } else {
          #pragma unroll
          for (int n = 0; n < 4; ++n) o[n] = acc[m][n][j] * rr2 * nwv[n];
        }
        if (valid) {
          u16* dst;
          if (mode == 3) dst = ck_bf + (size_t)s * HDIM + (wc & 1) * 64;
          else {
            u16* dstb = (mode == 0) ? q_out : lk_out;
            dst = dstb + ((size_t)((col0 >> 7) + hgrp) * S_LEN + s) * HDIM + (wc & 1) * 64;
          }
          #pragma unroll
          for (int n = 0; n < 4; ++n) dst[n * 16 + cl] = f2bf(o[n]);
        }
      }
  }
}

// ---------------- out GEMM: pipelined 128^2, counted 1-deep, XCD swizzle (R10 verified)
__global__ __launch_bounds__(256, 2) void k_gemm_out(const u16* __restrict__ A, const u16* __restrict__ Bt,
                                                     const float* __restrict__ bias, float* __restrict__ C) {
  __shared__ __align__(16) u16 lds[32768];     // 64 KB: 2 x 32 KB
  int tid = threadIdx.x, lane = tid & 63;
  int wave = tid >> 6;
  int wr = wave >> 1, wc = wave & 1;
  int lin = blockIdx.x + (blockIdx.y << 4);
  int swz = (lin & 7) * 32 + (lin >> 3);       // bijective 256 = 8*32
  int row0 = (swz & 15) * 128, col0 = (swz >> 4) * 128;
  int rA = lane & 15, kg = lane >> 4;
  int srow = tid >> 3, sslot = tid & 7;        // srow in [0,32)
  int ssl = sslot ^ (srow & 7);

  f32x4 acc[4][4];
  #pragma unroll
  for (int m = 0; m < 4; ++m)
    #pragma unroll
    for (int n = 0; n < 4; ++n) acc[m][n] = (f32x4){0.f, 0.f, 0.f, 0.f};

  auto stage = [&](int b, int i, int kt) {
    const u16* src = (i < 4) ? Bt : A;
    int rg = ((i < 4) ? col0 : row0) + (i & 3) * 32 + srow;
    int dofs = (i < 4) ? (8192 + i * 2048) : ((i - 4) * 2048);
    gl_lds16(&src[(size_t)rg * HIDN + kt * 64 + ssl * 8],
             &lds[b * 16384 + dofs + tid * 8]);
  };
  auto rdA = [&](int b, int m, int ks) -> short8 {
    int r = wr * 64 + m * 16 + rA;
    int slot = (ks * 4 + kg) ^ (r & 7);
    return *(const short8*)&lds[b * 16384 + r * 64 + slot * 8];
  };
  auto rdB = [&](int b, int n, int ks) -> short8 {
    int r = wc * 64 + n * 16 + rA;
    int slot = (ks * 4 + kg) ^ (r & 7);
    return *(const short8*)&lds[b * 16384 + 8192 + r * 64 + slot * 8];
  };

  #pragma unroll
  for (int i = 0; i < 8; ++i) stage(0, i, 0);

  short8 Af[4], Bf[4][2];
  for (int u = 0; u < NKT; ++u) {
    int cur = u & 1;
    bool pf = (u + 1 < NKT);
    if (pf) {
      #pragma unroll
      for (int i = 0; i < 8; ++i) stage(cur ^ 1, i, u + 1);
    }
    if (pf) asm volatile("s_waitcnt vmcnt(8)" ::: "memory");
    else    asm volatile("s_waitcnt vmcnt(0)" ::: "memory");
    __builtin_amdgcn_sched_barrier(0);
    __builtin_amdgcn_s_barrier();
    #pragma unroll
    for (int n = 0; n < 4; ++n) { Bf[n][0] = rdB(cur, n, 0); Bf[n][1] = rdB(cur, n, 1); }
    #pragma unroll
    for (int m = 0; m < 4; ++m) Af[m] = rdA(cur, m, 0);
    asm volatile("s_waitcnt lgkmcnt(0)" ::: "memory");
    __builtin_amdgcn_sched_barrier(0);
    __builtin_amdgcn_s_setprio(1);
    #pragma unroll
    for (int m = 0; m < 4; ++m)
      #pragma unroll
      for (int n = 0; n < 4; ++n)
        acc[m][n] = __builtin_amdgcn_mfma_f32_16x16x32_bf16(Af[m], Bf[n][0], acc[m][n], 0, 0, 0);
    __builtin_amdgcn_s_setprio(0);
    #pragma unroll
    for (int m = 0; m < 4; ++m) Af[m] = rdA(cur, m, 1);
    asm volatile("s_waitcnt lgkmcnt(0)" ::: "memory");
    __builtin_amdgcn_sched_barrier(0);
    __builtin_amdgcn_s_setprio(1);
    #pragma unroll
    for (int m = 0; m < 4; ++m)
      #pragma unroll
      for (int n = 0; n < 4; ++n)
        acc[m][n] = __builtin_amdgcn_mfma_f32_16x16x32_bf16(Af[m], Bf[n][1], acc[m][n], 0, 0, 0);
    __builtin_amdgcn_s_setprio(0);
    __builtin_amdgcn_s_barrier();
  }

  int rbase = kg * 4, cl = rA;
  #pragma unroll
  for (int m = 0; m < 4; ++m) {
    int rowb = row0 + wr * 64 + m * 16 + rbase;
    #pragma unroll
    for (int n = 0; n < 4; ++n) {
      int col = col0 + wc * 64 + n * 16 + cl;
      float bb = bias[col];
      #pragma unroll
      for (int j = 0; j < 4; ++j)
        C[(size_t)(rowb + j) * HIDN + col] = acc[m][n][j] + bb;
    }
  }
}

// ---------------- merged attention: compressed (+sink) then local, merged write
__global__ __launch_bounds__(256) void k_attn(const u16* __restrict__ q_bf, const u16* __restrict__ ck_bf,
                                              const u16* __restrict__ cv_t, const float* __restrict__ sink_k,
                                              const float* __restrict__ sink_v,
                                              const u16* __restrict__ lk_bf, const u16* __restrict__ lv_t,
                                              u16* __restrict__ merged) {
  __shared__ __align__(16) u16 kv[21760];
  __shared__ __align__(16) float sc[32][164];
  __shared__ __align__(16) u16 pb[32][168];
  int tid = threadIdx.x, lane = tid & 63, wave = tid >> 6;
  int lin = blockIdx.x;
  int sw = (lin & 7) * 128 + (lin >> 3);
  int s0 = (sw & 63) * 32, h = sw >> 6;
  const size_t hb = (size_t)h * S_LEN * HDIM;
  int rA = lane & 15, kg8 = (lane >> 4) * 8;
  int qt = wave & 1, wg = wave >> 1;

  short8 aq[4];
  #pragma unroll
  for (int c = 0; c < 4; ++c)
    aq[c] = *(const short8*)&q_bf[hb + (size_t)(s0 + qt * 16 + rA) * HDIM + c * 32 + kg8];

  // ======== compressed phase ========
  int cmax = s0 / 16 + 2; if (cmax > 128) cmax = 128;
  int nkeys = cmax + 1;
  int nkt = (nkeys + 15) >> 4, nkc = (nkeys + 31) >> 5;

  for (int i = tid; i < cmax * 16; i += 256) {
    int r = i >> 4, cz = (i & 15) * 8;
    *(uint4*)&kv[r * 136 + cz] = *(const uint4*)&ck_bf[r * HDIM + cz];
  }
  if (tid < 128) kv[cmax * 136 + tid] = f2bf(sink_k[h * HDIM + tid]);
  __syncthreads();

  for (int kt = wg; kt < nkt; kt += 2) {
    f32x4 a = (f32x4){0.f, 0.f, 0.f, 0.f};
    #pragma unroll
    for (int c = 0; c < 4; ++c) {
      short8 bk2 = *(const short8*)&kv[(kt * 16 + rA) * 136 + c * 32 + kg8];
      a = __builtin_amdgcn_mfma_f32_16x16x32_bf16(aq[c], bk2, a, 0, 0, 0);
    }
    int rq = qt * 16 + (lane >> 4) * 4;
    #pragma unroll
    for (int j = 0; j < 4; ++j) sc[rq + j][kt * 16 + rA] = a[j];
  }
  __syncthreads();

  { // softmax (8 lanes / row)
    int ql = tid >> 3, e = tid & 7, s = s0 + ql;
    int NK = nkc * 32;
    float m = -1e30f;
    for (int i = e; i < NK; i += 8) {
      if (i < nkeys) {
        float raw = sc[ql][i];
        bool valid = (i < cmax) ? (i * 16 + 15 <= s) : true;
        float v = valid ? raw * SCALE : -1e9f;
        sc[ql][i] = v;
        m = fmaxf(m, v);
      }
    }
    m = fmaxf(m, __shfl_xor(m, 1));
    m = fmaxf(m, __shfl_xor(m, 2));
    m = fmaxf(m, __shfl_xor(m, 4));
    float sum = 0.f;
    for (int i = e; i < NK; i += 8) {
      if (i < nkeys) {
        float pv = __expf(sc[ql][i] - m);
        sc[ql][i] = pv;
        sum += pv;
      }
    }
    sum += __shfl_xor(sum, 1);
    sum += __shfl_xor(sum, 2);
    sum += __shfl_xor(sum, 4);
    float inv = 1.f / sum;
    for (int i = e; i < NK; i += 8)
      pb[ql][i] = (i < nkeys) ? f2bf(sc[ql][i] * inv) : (u16)0;
  }
  __syncthreads();

  { // stage V^T (d x keys): uint4 bulk below cmax, scalar tail (sink + zeros)
    int d = tid & 127, half = tid >> 7;
    int ng = cmax >> 3;                       // full 8-col groups below cmax
    const u16* srcrow = cv_t + (size_t)d * NCHNK;
    for (int g = half; g < ng; g += 2)
      *(uint4*)&kv[d * 168 + g * 8] = *(const uint4*)&srcrow[g * 8];
    u16 sv = f2bf(sink_v[h * HDIM + d]);
    int NC = nkc * 32;
    for (int c = ng * 8 + half; c < NC; c += 2) {
      u16 v = (c < cmax) ? srcrow[c] : ((c == cmax) ? sv : (u16)0);
      kv[d * 168 + c] = v;
    }
  }
  __syncthreads();

  f32x4 po_c[4];
  #pragma unroll
  for (int n = 0; n < 4; ++n) po_c[n] = (f32x4){0.f, 0.f, 0.f, 0.f};
  for (int kc = 0; kc < nkc; ++kc) {
    short8 pfrag = *(const short8*)&pb[qt * 16 + rA][kc * 32 + kg8];
    #pragma unroll
    for (int n = 0; n < 4; ++n) {
      short8 av = *(const short8*)&kv[(wg * 64 + n * 16 + rA) * 168 + kc * 32 + kg8];
      po_c[n] = __builtin_amdgcn_mfma_f32_16x16x32_bf16(av, pfrag, po_c[n], 0, 0, 0);
    }
  }
  __syncthreads();

  // ======== local phase ========
  int tbase = s0 - 128;
  for (int i = tid; i < 160 * 16; i += 256) {
    int r = i >> 4, cz = (i & 15) * 8;
    int t = tbase + r;
    uint4 val = make_uint4(0, 0, 0, 0);
    if (t >= 0) val = *(const uint4*)&lk_bf[hb + (size_t)t * HDIM + cz];
    *(uint4*)&kv[r * 136 + cz] = val;
  }
  __syncthreads();

  for (int kt = wg; kt < 10; kt += 2) {
    f32x4 a = (f32x4){0.f, 0.f, 0.f, 0.f};
    #pragma unroll
    for (int c = 0; c < 4; ++c) {
      short8 bk2 = *(const short8*)&kv[(kt * 16 + rA) * 136 + c * 32 + kg8];
      a = __builtin_amdgcn_mfma_f32_16x16x32_bf16(aq[c], bk2, a, 0, 0, 0);
    }
    int rq = qt * 16 + (lane >> 4) * 4;
    #pragma unroll
    for (int j = 0; j < 4; ++j) sc[rq + j][kt * 16 + rA] = a[j];
  }
  __syncthreads();

  {
    int ql = tid >> 3, e = tid & 7;
    int ilo = 128 - s0; if (ql > ilo) ilo = ql;
    int ihi = ql + 128;
    float m = -1e30f;
    for (int i = e; i < 160; i += 8) {
      bool valid = (i >= ilo) && (i <= ihi);
      float v = valid ? sc[ql][i] * SCALE : -1e9f;
      sc[ql][i] = v;
      m = fmaxf(m, v);
    }
    m = fmaxf(m, __shfl_xor(m, 1));
    m = fmaxf(m, __shfl_xor(m, 2));
    m = fmaxf(m, __shfl_xor(m, 4));
    float sum = 0.f;
    for (int i = e; i < 160; i += 8) {
      float pv = __expf(sc[ql][i] - m);
      sc[ql][i] = pv;
      sum += pv;
    }
    sum += __shfl_xor(sum, 1);
    sum += __shfl_xor(sum, 2);
    sum += __shfl_xor(sum, 4);
    float inv = 1.f / sum;
    for (int i = e; i < 160; i += 8) pb[ql][i] = f2bf(sc[ql][i] * inv);
  }
  __syncthreads();

  {
    int d = tid & 127, c8s = tid >> 7;
    const size_t hbt = (size_t)h * HDIM * S_LEN;
    for (int c8 = c8s; c8 < 20; c8 += 2) {
      int t0 = tbase + c8 * 8;
      uint4 val = make_uint4(0, 0, 0, 0);
      if (t0 >= 0) val = *(const uint4*)&lv_t[hbt + (size_t)d * S_LEN + t0];
      *(uint4*)&kv[d * 168 + c8 * 8] = val;
    }
  }
  __syncthreads();

  {
    f32x4 po[4];
    #pragma unroll
    for (int n = 0; n < 4; ++n) po[n] = (f32x4){0.f, 0.f, 0.f, 0.f};
    #pragma unroll
    for (int kc = 0; kc < 5; ++kc) {
      short8 pfrag = *(const short8*)&pb[qt * 16 + rA][kc * 32 + kg8];
      #pragma unroll
      for (int n = 0; n < 4; ++n) {
        short8 av = *(const short8*)&kv[(wg * 64 + n * 16 + rA) * 168 + kc * 32 + kg8];
        po[n] = __builtin_amdgcn_mfma_f32_16x16x32_bf16(av, pfrag, po[n], 0, 0, 0);
      }
    }
    int q = qt * 16 + rA;
    int s = s0 + q;
    int rb = (lane >> 4) * 4;
    #pragma unroll
    for (int n = 0; n < 4; ++n) {
      int d0 = wg * 64 + n * 16 + rb;
      ushort4 o;
      o.x = f2bf(0.5f * (po[n][0] + po_c[n][0]));
      o.y = f2bf(0.5f * (po[n][1] + po_c[n][1]));
      o.z = f2bf(0.5f * (po[n][2] + po_c[n][2]));
      o.w = f2bf(0.5f * (po[n][3] + po_c[n][3]));
      *(ushort4*)&merged[(size_t)s * HIDN + h * HDIM + d0] = o;
    }
  }
}

extern "C" void kernel_launch(void* const* d_in, const int* in_sizes, int n_in,
                              void* d_out, int out_size, void* d_ws, size_t ws_size,
                              hipStream_t stream) {
  const float* hs     = (const float*)d_in[0];
  const float* Wq     = (const float*)d_in[1];
  const float* bq     = (const float*)d_in[2];
  const float* Wc     = (const float*)d_in[3];
  const float* bc     = (const float*)d_in[4];
  const float* Wk     = (const float*)d_in[5];
  const float* bk     = (const float*)d_in[6];
  const float* Wv     = (const float*)d_in[7];
  const float* bv     = (const float*)d_in[8];
  const float* Wlk    = (const float*)d_in[9];
  const float* blk    = (const float*)d_in[10];
  const float* Wlv    = (const float*)d_in[11];
  const float* blv    = (const float*)d_in[12];
  const float* qn_w   = (const float*)d_in[13];
  const float* kn_w   = (const float*)d_in[14];
  const float* sink_k = (const float*)d_in[15];
  const float* sink_v = (const float*)d_in[16];
  const float* Wo     = (const float*)d_in[17];
  const float* bo     = (const float*)d_in[18];
  float* out = (float*)d_out;

  char* p = (char*)d_ws;
  auto alloc = [&](size_t bytes) {
    char* r = p;
    p += (bytes + 255) & ~(size_t)255;
    return r;
  };
  float* rope_c  = (float*)alloc((size_t)S_LEN * 32 * 4);
  float* rope_s  = (float*)alloc((size_t)S_LEN * 32 * 4);
  u16*   hs_bf   = (u16*)  alloc((size_t)S_LEN * HIDN * 2);
  u16*   Wt3     = (u16*)  alloc((size_t)3 * HIDN * HIDN * 2);
  u16*   Wt_o    = (u16*)  alloc((size_t)HIDN * HIDN * 2);
  u16*   Wkv_t   = (u16*)  alloc((size_t)2 * HDIM * HIDN * 2);
  u16*   ent_bf  = (u16*)  alloc((size_t)256 * HIDN * 2);
  u16*   q_bf    = (u16*)  alloc((size_t)NHEAD * S_LEN * HDIM * 2);
  u16*   lk_bf   = (u16*)  alloc((size_t)NHEAD * S_LEN * HDIM * 2);
  u16*   lv_t    = (u16*)  alloc((size_t)NHEAD * HDIM * S_LEN * 2);
  u16*   ck_bf   = (u16*)  alloc((size_t)NCHNK * HDIM * 2);
  u16*   cv_t    = (u16*)  alloc((size_t)HDIM * NCHNK * 2);
  u16*   merged  = (u16*)  alloc((size_t)S_LEN * HIDN * 2);
  (void)ws_size; (void)in_sizes; (void)n_in; (void)out_size;

  // all preprocessing in one dispatch
  k_pre<<<dim3(64, 64, 6), dim3(32, 8), 0, stream>>>(Wq, Wlk, Wlv, Wo, hs, Wc, bc, Wk, Wv,
                                                     Wt3, Wt_o, hs_bf, rope_c, rope_s,
                                                     ent_bf, Wkv_t);

  // fused q/lk/lv + ck/cv projections (R9 pipelined 256^2)
  k_gemm256<<<193, 512, 0, stream>>>(hs_bf, Wt3, ent_bf, Wkv_t,
                                     bq, blk, blv, bk, bv, qn_w, kn_w,
                                     rope_c, rope_s, q_bf, lk_bf, lv_t, ck_bf, cv_t);

  // merged attention (compressed + local + merge), XCD-chunked
  k_attn<<<1024, 256, 0, stream>>>(q_bf, ck_bf, cv_t, sink_k, sink_v,
                                   lk_bf, lv_t, merged);

  // output projection (pipelined 128^2)
  k_gemm_out<<<dim3(16, 16), 256, 0, stream>>>(merged, Wt_o, bo, out);
}